// Round 8
// baseline (1313.370 us; speedup 1.0000x reference)
//
#include <hip/hip_runtime.h>
#include <math.h>

#define N_ATOMS 20000
#define N_CG    1000
#define N_EDGES 200000
#define FEAT    128
#define NRBF    20
#define NCONV   3
#define CUTOFF  5.0f
#define PLANE   (N_ATOMS * FEAT)      // 2,560,000
#define PI_F    3.14159265358979323846f
#define LDH     130                   // LDS H stride (f32) — bank-conflict-safe

#define PACK_PER_CONV 212992          // ushorts per conv in each of packH/packL

typedef __attribute__((ext_vector_type(8))) short bf16x8;
typedef __attribute__((ext_vector_type(4))) float f32x4;

__device__ __forceinline__ void split2(float x, ushort& h, ushort& l)
{
    unsigned u  = __float_as_uint(x);
    unsigned hb = (u + 0x7FFFu + ((u >> 16) & 1u)) & 0xFFFF0000u;
    float    hf = __uint_as_float(hb);
    float    lf = x - hf;                       // exact
    unsigned ul = __float_as_uint(lf);
    h = (ushort)(hb >> 16);
    l = (ushort)((ul + 0x7FFFu + ((ul >> 16) & 1u)) >> 16);
}

// interleaved packed v: one uint = (hi<<16)|lo; recon == hi-part + lo-part
__device__ __forceinline__ float reconP(unsigned u)
{
    return __uint_as_float(u & 0xFFFF0000u) + __uint_as_float(u << 16);
}

__device__ __forceinline__ unsigned packP(float x)
{
    ushort h, l;
    split2(x, h, l);
    return ((unsigned)h << 16) | l;
}

__device__ __forceinline__ void splitv8(const float* hv, bf16x8& ah, bf16x8& al)
{
#pragma unroll
    for (int j = 0; j < 8; ++j) {
        ushort h, l;
        split2(hv[j], h, l);
        ah[j] = (short)h; al[j] = (short)l;
    }
}

// unpack 8 interleaved uints -> hi/lo bf16x8 fragments
__device__ __forceinline__ void unpack8(const unsigned* __restrict__ p,
                                        bf16x8& ah, bf16x8& al)
{
#pragma unroll
    for (int j = 0; j < 8; ++j) {
        unsigned u = p[j];
        ah[j] = (short)(u >> 16);
        al[j] = (short)(u & 0xFFFFu);
    }
}

// 3-MFMA split product accumulate
#define MFMA3(ACC, AH_, AL_, BH_, BL_)                                              \
    ACC = __builtin_amdgcn_mfma_f32_16x16x32_bf16(AH_, BH_, ACC, 0, 0, 0);          \
    ACC = __builtin_amdgcn_mfma_f32_16x16x32_bf16(AH_, BL_, ACC, 0, 0, 0);          \
    ACC = __builtin_amdgcn_mfma_f32_16x16x32_bf16(AL_, BH_, ACC, 0, 0, 0);

// ---------------------------------------------------------------------------
// Fused MLP: C = (swish(A @ B1 + b1)) @ B2 + b2[bcol0:].  Used only for the
// initial phi0 (from k_s_init's packed s).
// ---------------------------------------------------------------------------
template<int K1, int N2>
__global__ __launch_bounds__(256)
void mlp_fused(const ushort* __restrict__ AH, const ushort* __restrict__ AL,
               const ushort* __restrict__ B1h, const ushort* __restrict__ B1l,
               const float* __restrict__ b1,
               const ushort* __restrict__ B2h, const ushort* __restrict__ B2l,
               const float* __restrict__ b2, int bcol0,
               float* __restrict__ C)
{
    __shared__ float Hs[32 * LDH];
    const int tid  = threadIdx.x;
    const int lane = tid & 63;
    const int w    = tid >> 6;
    const int wm   = w & 1, wn = w >> 1;
    const int m0   = blockIdx.x * 32;
    const int l15  = lane & 15;
    const int koff = (lane >> 4) * 8;
    const int rowb = wm * 16;                   // local row base
    const int q4   = (lane >> 4) * 4;

    // ---- phase 1: H = swish(A @ B1 + b1) (N1 = 128) ----
    f32x4 acc1[4];
#pragma unroll
    for (int j = 0; j < 4; ++j) acc1[j] = (f32x4){0.f, 0.f, 0.f, 0.f};
#pragma unroll
    for (int k0 = 0; k0 < K1; k0 += 32) {
        size_t aa = (size_t)(m0 + rowb + l15) * K1 + k0 + koff;
        bf16x8 ah = *reinterpret_cast<const bf16x8*>(AH + aa);
        bf16x8 al = *reinterpret_cast<const bf16x8*>(AL + aa);
#pragma unroll
        for (int nf = 0; nf < 4; ++nf) {
            size_t ba = (size_t)(wn * 64 + nf * 16 + l15) * K1 + k0 + koff;
            bf16x8 bh = *reinterpret_cast<const bf16x8*>(B1h + ba);
            bf16x8 bl = *reinterpret_cast<const bf16x8*>(B1l + ba);
            MFMA3(acc1[nf], ah, al, bh, bl);
        }
    }
#pragma unroll
    for (int nf = 0; nf < 4; ++nf) {
        int col = wn * 64 + nf * 16 + l15;
        float bv = b1[col];
#pragma unroll
        for (int r = 0; r < 4; ++r) {
            float x = acc1[nf][r] + bv;
            x = x / (1.f + __expf(-x));         // swish
            Hs[(rowb + q4 + r) * LDH + col] = x;
        }
    }
    __syncthreads();

    // ---- phase 2: C = H @ B2 + b2 ----
    constexpr int NF2  = N2 / 32;               // frags per wave
    constexpr int WCOL = N2 / 2;
    f32x4 acc2[NF2];
#pragma unroll
    for (int j = 0; j < NF2; ++j) acc2[j] = (f32x4){0.f, 0.f, 0.f, 0.f};
#pragma unroll
    for (int k0 = 0; k0 < 128; k0 += 32) {
        const float* hp = &Hs[(rowb + l15) * LDH + k0 + koff];
        float hv[8];
#pragma unroll
        for (int j = 0; j < 8; ++j) hv[j] = hp[j];
        bf16x8 ah, al;
        splitv8(hv, ah, al);
#pragma unroll
        for (int nf = 0; nf < NF2; ++nf) {
            size_t ba = (size_t)(wn * WCOL + nf * 16 + l15) * 128 + k0 + koff;
            bf16x8 bh = *reinterpret_cast<const bf16x8*>(B2h + ba);
            bf16x8 bl = *reinterpret_cast<const bf16x8*>(B2l + ba);
            MFMA3(acc2[nf], ah, al, bh, bl);
        }
    }
#pragma unroll
    for (int nf = 0; nf < NF2; ++nf) {
        int col = wn * WCOL + nf * 16 + l15;
        float bv = b2 ? b2[bcol0 + col] : 0.f;
#pragma unroll
        for (int r = 0; r < 4; ++r) {
            int row = m0 + rowb + q4 + r;
            C[(size_t)row * N2 + col] = acc2[nf][r] + bv;
        }
    }
}

// ---------------------------------------------------------------------------
// r8 MEGA kernel: vnorm + stack-MLP + u/update + (dual MLP on the new s).
// r7's mlp_dual read the packed s that mega had just written to HBM — but
// each mega block OWNS those 32 rows.  Phase C now writes the new packed s
// into LDS; phases D1/D2 run the next-conv msg MLP (HAS_MSG) and this conv's
// CG MLP in-block.  Removes 1 launch/conv + the global sH/sL round-trip.
// LDS: region0 Hs/Hm (16640B) | region1 nH,nL -> sHs,sLs (16384B) |
//      region2 Hc (16640B) = 49664B total.
// ---------------------------------------------------------------------------
template<int HAS_MSG>
__global__ __launch_bounds__(256)
void k_update_mega(unsigned* __restrict__ vP,
                   const ushort* __restrict__ catH, const ushort* __restrict__ catL,
                   const ushort* __restrict__ BVh, const ushort* __restrict__ BVl,
                   const ushort* __restrict__ W1h, const ushort* __restrict__ W1l,
                   const float*  __restrict__ b1,
                   const ushort* __restrict__ W2h, const ushort* __restrict__ W2l,
                   const float*  __restrict__ b2,
                   const ushort* __restrict__ BUh, const ushort* __restrict__ BUl,
                   float* __restrict__ s,
                   const ushort* __restrict__ M1h, const ushort* __restrict__ M1l,
                   const float*  __restrict__ m1b,
                   const ushort* __restrict__ M2h, const ushort* __restrict__ M2l,
                   const float*  __restrict__ m2b,
                   const ushort* __restrict__ C1h, const ushort* __restrict__ C1l,
                   const float*  __restrict__ c1b,
                   const ushort* __restrict__ C2h, const ushort* __restrict__ C2l,
                   const float*  __restrict__ c2b,      // full 384; cols 128.. used
                   float* __restrict__ phi, float* __restrict__ uv)
{
    __shared__ __align__(16) char smem[16640 + 16384 + 16640];
    float*  Hs  = (float*)smem;                          // region0 (also Hm)
    ushort* nH  = (ushort*)(smem + 16640);               // region1
    ushort* nL  = (ushort*)(smem + 16640 + 8192);
    ushort* sHs = nH;                                    // region1 reuse (post-B1)
    ushort* sLs = nL;
    float*  Hc  = (float*)(smem + 16640 + 16384);        // region2

    const int tid  = threadIdx.x;
    const int lane = tid & 63;
    const int w    = tid >> 6;
    const int wm   = w & 1, wn = w >> 1;
    const int m0   = blockIdx.x * 32;
    const int l15  = lane & 15;
    const int koff = (lane >> 4) * 8;
    const int rowb = wm * 16;
    const int q4   = (lane >> 4) * 4;

    // ---- phase A: dual GEMM (vv = v@V, uv = v@U) with a single A pass ----
    f32x4 accV[3][4], accU[3][4];
#pragma unroll
    for (int d = 0; d < 3; ++d)
#pragma unroll
        for (int j = 0; j < 4; ++j) {
            accV[d][j] = (f32x4){0.f, 0.f, 0.f, 0.f};
            accU[d][j] = (f32x4){0.f, 0.f, 0.f, 0.f};
        }
    for (int k0 = 0; k0 < 128; k0 += 32) {
        bf16x8 ah[3], al[3];
#pragma unroll
        for (int d = 0; d < 3; ++d) {
            size_t aa = (size_t)d * PLANE + (size_t)(m0 + rowb + l15) * 128 + k0 + koff;
            unsigned u[8];
#pragma unroll
            for (int j = 0; j < 8; ++j) u[j] = vP[aa + j];
            unpack8(u, ah[d], al[d]);
        }
#pragma unroll
        for (int nf = 0; nf < 4; ++nf) {
            size_t ba = (size_t)(wn * 64 + nf * 16 + l15) * 128 + k0 + koff;
            bf16x8 bvh = *reinterpret_cast<const bf16x8*>(BVh + ba);
            bf16x8 bvl = *reinterpret_cast<const bf16x8*>(BVl + ba);
            bf16x8 buh = *reinterpret_cast<const bf16x8*>(BUh + ba);
            bf16x8 bul = *reinterpret_cast<const bf16x8*>(BUl + ba);
#pragma unroll
            for (int d = 0; d < 3; ++d) {
                MFMA3(accV[d][nf], ah[d], al[d], bvh, bvl);
            }
#pragma unroll
            for (int d = 0; d < 3; ++d) {
                MFMA3(accU[d][nf], ah[d], al[d], buh, bul);
            }
        }
    }
    // norm -> LDS (C-layout)
#pragma unroll
    for (int nf = 0; nf < 4; ++nf) {
        int col = wn * 64 + nf * 16 + l15;
#pragma unroll
        for (int r = 0; r < 4; ++r) {
            int lrow = rowb + q4 + r;
            float x = accV[0][nf][r], y = accV[1][nf][r], z = accV[2][nf][r];
            float nrm = sqrtf(x * x + y * y + z * z + 3e-15f);
            ushort h, l;
            split2(nrm, h, l);
            nH[lrow * 128 + col] = h;
            nL[lrow * 128 + col] = l;
        }
    }
    __syncthreads();

    // ---- phase B1: H = swish([Ccat_s | norm] @ W1 + b1), K1 = 256 ----
    f32x4 acc1[4];
#pragma unroll
    for (int j = 0; j < 4; ++j) acc1[j] = (f32x4){0.f, 0.f, 0.f, 0.f};
#pragma unroll 2
    for (int k0 = 0; k0 < 256; k0 += 32) {
        bf16x8 ah, al;
        if (k0 < 128) {
            size_t aa = (size_t)(m0 + rowb + l15) * 128 + k0 + koff;
            ah = *reinterpret_cast<const bf16x8*>(catH + aa);
            al = *reinterpret_cast<const bf16x8*>(catL + aa);
        } else {
            int la = (rowb + l15) * 128 + (k0 - 128) + koff;
            ah = *reinterpret_cast<const bf16x8*>(nH + la);
            al = *reinterpret_cast<const bf16x8*>(nL + la);
        }
#pragma unroll
        for (int nf = 0; nf < 4; ++nf) {
            size_t ba = (size_t)(wn * 64 + nf * 16 + l15) * 256 + k0 + koff;
            bf16x8 bh = *reinterpret_cast<const bf16x8*>(W1h + ba);
            bf16x8 bl = *reinterpret_cast<const bf16x8*>(W1l + ba);
            MFMA3(acc1[nf], ah, al, bh, bl);
        }
    }
#pragma unroll
    for (int nf = 0; nf < 4; ++nf) {
        int col = wn * 64 + nf * 16 + l15;
        float bv = b1[col];
#pragma unroll
        for (int r = 0; r < 4; ++r) {
            float x = acc1[nf][r] + bv;
            x = x / (1.f + __expf(-x));         // swish
            Hs[(rowb + q4 + r) * LDH + col] = x;
        }
    }
    __syncthreads();   // nH/nL reads done block-wide; region1 reusable below

    // ---- phase B2: stack fragments IN REGISTERS, wave-aligned to phase C ----
    // group g: 0=avv, 1=asv, 2=ass; col = g*128 + wn*64 + j*16 + l15
    f32x4 acc2[12];
#pragma unroll
    for (int j = 0; j < 12; ++j) acc2[j] = (f32x4){0.f, 0.f, 0.f, 0.f};
    for (int k0 = 0; k0 < 128; k0 += 32) {
        const float* hp = &Hs[(rowb + l15) * LDH + k0 + koff];
        float hv[8];
#pragma unroll
        for (int j = 0; j < 8; ++j) hv[j] = hp[j];
        bf16x8 ah, al;
        splitv8(hv, ah, al);
#pragma unroll
        for (int g = 0; g < 3; ++g) {
#pragma unroll
            for (int j = 0; j < 4; ++j) {
                size_t ba = (size_t)(g * 128 + wn * 64 + j * 16 + l15) * 128 + k0 + koff;
                bf16x8 bh = *reinterpret_cast<const bf16x8*>(W2h + ba);
                bf16x8 bl = *reinterpret_cast<const bf16x8*>(W2l + ba);
                MFMA3(acc2[g * 4 + j], ah, al, bh, bl);
            }
        }
    }

    // ---- phase C: update rule; new packed s goes to LDS (region1) ----
#pragma unroll
    for (int nf = 0; nf < 4; ++nf) {
        int col = wn * 64 + nf * 16 + l15;
        float bavv = b2[col];
        float basv = b2[128 + col];
        float bass = b2[256 + col];
#pragma unroll
        for (int r = 0; r < 4; ++r) {
            int lrow = rowb + q4 + r;
            int row  = m0 + lrow;
            size_t idx = (size_t)row * FEAT + col;
            float avv = acc2[nf][r]     + bavv;
            float asv = acc2[4 + nf][r] + basv;
            float ass = acc2[8 + nf][r] + bass;
            float u0 = accU[0][nf][r], u1 = accU[1][nf][r], u2 = accU[2][nf][r];
            float w0 = accV[0][nf][r], w1 = accV[1][nf][r], w2 = accV[2][nf][r];
            float dot = u0 * w0 + u1 * w1 + u2 * w2;
            float n0 = reconP(vP[idx])                      + u0 * avv;
            float n1 = reconP(vP[PLANE + idx])              + u1 * avv;
            float n2 = reconP(vP[2 * (size_t)PLANE + idx])  + u2 * avv;
            vP[idx] = packP(n0);
            vP[PLANE + idx] = packP(n1);
            vP[2 * (size_t)PLANE + idx] = packP(n2);
            float ns = s[idx] + dot * asv + ass;
            s[idx] = ns;
            ushort h, l;
            split2(ns, h, l);
            sHs[lrow * 128 + col] = h;
            sLs[lrow * 128 + col] = l;
        }
    }
    __syncthreads();

    // ---- phase D1: hidden layers of msg (next conv) and cg MLPs from LDS s ----
    f32x4 am[4], ac[4];
#pragma unroll
    for (int j = 0; j < 4; ++j) {
        am[j] = (f32x4){0.f, 0.f, 0.f, 0.f};
        ac[j] = (f32x4){0.f, 0.f, 0.f, 0.f};
    }
#pragma unroll
    for (int k0 = 0; k0 < 128; k0 += 32) {
        int la = (rowb + l15) * 128 + k0 + koff;
        bf16x8 ah = *reinterpret_cast<const bf16x8*>(sHs + la);
        bf16x8 al = *reinterpret_cast<const bf16x8*>(sLs + la);
#pragma unroll
        for (int nf = 0; nf < 4; ++nf) {
            size_t ba = (size_t)(wn * 64 + nf * 16 + l15) * 128 + k0 + koff;
            if (HAS_MSG) {
                bf16x8 bh = *reinterpret_cast<const bf16x8*>(M1h + ba);
                bf16x8 bl = *reinterpret_cast<const bf16x8*>(M1l + ba);
                MFMA3(am[nf], ah, al, bh, bl);
            }
            bf16x8 ch = *reinterpret_cast<const bf16x8*>(C1h + ba);
            bf16x8 cl = *reinterpret_cast<const bf16x8*>(C1l + ba);
            MFMA3(ac[nf], ah, al, ch, cl);
        }
    }
#pragma unroll
    for (int nf = 0; nf < 4; ++nf) {
        int col = wn * 64 + nf * 16 + l15;
        float bvc = c1b[col];
        float bvm = HAS_MSG ? m1b[col] : 0.f;
#pragma unroll
        for (int r = 0; r < 4; ++r) {
            int lr = rowb + q4 + r;
            if (HAS_MSG) {
                float x = am[nf][r] + bvm;
                Hs[lr * LDH + col] = x / (1.f + __expf(-x));   // Hm (region0)
            }
            float y = ac[nf][r] + bvc;
            Hc[lr * LDH + col] = y / (1.f + __expf(-y));
        }
    }
    __syncthreads();

    // ---- phase D2: phi (384, msg) and uv (128, cg) ----
    f32x4 a2m[12], a2c[4];
    if (HAS_MSG) {
#pragma unroll
        for (int j = 0; j < 12; ++j) a2m[j] = (f32x4){0.f, 0.f, 0.f, 0.f};
    }
#pragma unroll
    for (int j = 0; j < 4; ++j)  a2c[j] = (f32x4){0.f, 0.f, 0.f, 0.f};
#pragma unroll
    for (int k0 = 0; k0 < 128; k0 += 32) {
        const float* hpc = &Hc[(rowb + l15) * LDH + k0 + koff];
        float hvc[8];
#pragma unroll
        for (int j = 0; j < 8; ++j) hvc[j] = hpc[j];
        bf16x8 ahc, alc;
        splitv8(hvc, ahc, alc);
#pragma unroll
        for (int nf = 0; nf < 4; ++nf) {
            size_t ba = (size_t)(wn * 64 + nf * 16 + l15) * 128 + k0 + koff;
            bf16x8 bh = *reinterpret_cast<const bf16x8*>(C2h + ba);
            bf16x8 bl = *reinterpret_cast<const bf16x8*>(C2l + ba);
            MFMA3(a2c[nf], ahc, alc, bh, bl);
        }
        if (HAS_MSG) {
            const float* hpm = &Hs[(rowb + l15) * LDH + k0 + koff];
            float hvm[8];
#pragma unroll
            for (int j = 0; j < 8; ++j) hvm[j] = hpm[j];
            bf16x8 ahm, alm;
            splitv8(hvm, ahm, alm);
#pragma unroll
            for (int nf = 0; nf < 12; ++nf) {
                size_t ba = (size_t)(wn * 192 + nf * 16 + l15) * 128 + k0 + koff;
                bf16x8 bh = *reinterpret_cast<const bf16x8*>(M2h + ba);
                bf16x8 bl = *reinterpret_cast<const bf16x8*>(M2l + ba);
                MFMA3(a2m[nf], ahm, alm, bh, bl);
            }
        }
    }
    if (HAS_MSG) {
#pragma unroll
        for (int nf = 0; nf < 12; ++nf) {
            int col = wn * 192 + nf * 16 + l15;
            float bv = m2b[col];
#pragma unroll
            for (int r = 0; r < 4; ++r) {
                int row = m0 + rowb + q4 + r;
                phi[(size_t)row * 384 + col] = a2m[nf][r] + bv;
            }
        }
    }
#pragma unroll
    for (int nf = 0; nf < 4; ++nf) {
        int col = wn * 64 + nf * 16 + l15;
        float bv = c2b[128 + col];
#pragma unroll
        for (int r = 0; r < 4; ++r) {
            int row = m0 + rowb + q4 + r;
            uv[(size_t)row * 128 + col] = a2c[nf][r] + bv;
        }
    }
}

// ---------------------------------------------------------------------------
// Weight pre-pack: fp32 W[k][col0+n] -> bf16 hi/lo at [n][k] (k-contiguous).
// ---------------------------------------------------------------------------
__global__ void k_pack_all(const float* __restrict__ msg_W1, const float* __restrict__ msg_W2,
                           const float* __restrict__ upd_V,  const float* __restrict__ upd_W1,
                           const float* __restrict__ upd_W2, const float* __restrict__ upd_U,
                           const float* __restrict__ cg_W1,  const float* __restrict__ cg_W2,
                           ushort* __restrict__ Bh, ushort* __restrict__ Bl)
{
    const int wid = blockIdx.y, conv = blockIdx.z;
    const float* W; int K, N, ldw, col0; size_t off;
    switch (wid) {
        case 0: W = msg_W1 + (size_t)conv * 16384; K = 128; N = 128; ldw = 128; col0 = 0;   off = 0;      break;
        case 1: W = msg_W2 + (size_t)conv * 49152; K = 128; N = 384; ldw = 384; col0 = 0;   off = 16384;  break;
        case 2: W = upd_V  + (size_t)conv * 16384; K = 128; N = 128; ldw = 128; col0 = 0;   off = 65536;  break;
        case 3: W = upd_W1 + (size_t)conv * 32768; K = 256; N = 128; ldw = 128; col0 = 0;   off = 81920;  break;
        case 4: W = upd_W2 + (size_t)conv * 49152; K = 128; N = 384; ldw = 384; col0 = 0;   off = 114688; break;
        case 5: W = upd_U  + (size_t)conv * 16384; K = 128; N = 128; ldw = 128; col0 = 0;   off = 163840; break;
        case 6: W = cg_W1  + (size_t)conv * 16384; K = 128; N = 128; ldw = 128; col0 = 0;   off = 180224; break;
        default:W = cg_W2  + (size_t)conv * 49152; K = 128; N = 128; ldw = 384; col0 = 128; off = 196608; break;
    }
    off += (size_t)conv * PACK_PER_CONV;
    int idx = blockIdx.x * 256 + threadIdx.x;
    if (idx >= K * N) return;
    int k = idx & (K - 1);
    int n = idx >> ((K == 256) ? 8 : 7);
    ushort h, l;
    split2(W[(size_t)k * ldw + col0 + n], h, l);
    Bh[off + (size_t)n * K + k] = h;
    Bl[off + (size_t)n * K + k] = l;
}

// ---------------------------------------------------------------------------
// Setup kernels
// ---------------------------------------------------------------------------
__global__ void k_s_init(const int* __restrict__ z, const float* __restrict__ embed,
                         float* __restrict__ s, ushort* __restrict__ sH, ushort* __restrict__ sL)
{
    int idx = blockIdx.x * blockDim.x + threadIdx.x;
    if (idx >= PLANE) return;
    int n = idx >> 7, g = idx & 127;
    float e = embed[z[n] * FEAT + g];
    s[idx] = e;
    ushort h, l;
    split2(e, h, l);
    sH[idx] = h; sL[idx] = l;
}

__global__ void k_atom_geo(const int* __restrict__ mapping,
                           const float* __restrict__ xyz, const float* __restrict__ cg_xyz,
                           float* __restrict__ rbf_a, float* __restrict__ env_a,
                           float* __restrict__ cnt)
{
    int n = blockIdx.x * blockDim.x + threadIdx.x;
    if (n >= N_ATOMS) return;
    int m = mapping[n];
    float dx = xyz[n * 3 + 0] - cg_xyz[m * 3 + 0];
    float dy = xyz[n * 3 + 1] - cg_xyz[m * 3 + 1];
    float dz = xyz[n * 3 + 2] - cg_xyz[m * 3 + 2];
    float d = sqrtf(dx * dx + dy * dy + dz * dz + 3e-15f);
    float env = (d < CUTOFF) ? 0.5f * (cosf(PI_F * d / CUTOFF) + 1.f) : 0.f;
    env_a[n] = env;
    float s = env / d;
#pragma unroll
    for (int k = 0; k < NRBF; ++k)
        rbf_a[n * NRBF + k] = sinf((k + 1) * PI_F * d / CUTOFF) * s;
    atomicAdd(&cnt[m], 1.f);
}

// ---------------------------------------------------------------------------
// CSR build
// ---------------------------------------------------------------------------
__global__ void k_deg(const int* __restrict__ nbr, int* __restrict__ deg)
{
    int e = blockIdx.x * blockDim.x + threadIdx.x;
    if (e < N_EDGES) atomicAdd(&deg[nbr[2 * e]], 1);
}

__global__ __launch_bounds__(1024)
void k_scan(const int* __restrict__ deg, int* __restrict__ rowptr)
{
    __shared__ int sh[1024];
    const int chunk = (N_ATOMS + 1023) / 1024;
    int t = threadIdx.x;
    int base = t * chunk;
    int sum = 0;
    for (int i = 0; i < chunk; ++i) {
        int idx = base + i;
        if (idx < N_ATOMS) sum += deg[idx];
    }
    sh[t] = sum;
    __syncthreads();
    for (int off = 1; off < 1024; off <<= 1) {
        int val = (t >= off) ? sh[t - off] : 0;
        __syncthreads();
        sh[t] += val;
        __syncthreads();
    }
    int run = (t == 0) ? 0 : sh[t - 1];
    for (int i = 0; i < chunk; ++i) {
        int idx = base + i;
        if (idx < N_ATOMS) { rowptr[idx] = run; run += deg[idx]; }
    }
}

__global__ void k_fill(const int* __restrict__ nbr, const float* __restrict__ xyz,
                       const int* __restrict__ rowptr, int* __restrict__ cursor,
                       int* __restrict__ rec_dst, float4* __restrict__ rec_u4,
                       float* __restrict__ rec_rbf)
{
    int e = blockIdx.x * blockDim.x + threadIdx.x;
    if (e >= N_EDGES) return;
    int src = nbr[2 * e], dst = nbr[2 * e + 1];
    int pos = atomicAdd(&cursor[src], 1);
    int q = rowptr[src] + pos;
    float dx = xyz[dst * 3 + 0] - xyz[src * 3 + 0];
    float dy = xyz[dst * 3 + 1] - xyz[src * 3 + 1];
    float dz = xyz[dst * 3 + 2] - xyz[src * 3 + 2];
    float d = sqrtf(dx * dx + dy * dy + dz * dz + 3e-15f);
    float env = (d < CUTOFF) ? 0.5f * (cosf(PI_F * d / CUTOFF) + 1.f) : 0.f;
    rec_dst[q] = dst;
    rec_u4[q] = make_float4(dx / d, dy / d, dz / d, env);
    float sc = env / d;
#pragma unroll
    for (int k = 0; k < NRBF; ++k)
        rec_rbf[(size_t)q * NRBF + k] = sinf((k + 1) * PI_F * d / CUTOFF) * sc;
}

// ---------------------------------------------------------------------------
// Edge segment-sum (r2 slot-per-atom, r4 2-edge ILP, r6 interleaved packed v).
// At its memory-path floor (~313 MB L2-miss stream, invariant r0-r7).
// ---------------------------------------------------------------------------
#define EDGE_BLOCKS 2500
__global__ __launch_bounds__(512, 2)
void k_edge_seg(const int* __restrict__ rowptr, const int* __restrict__ deg,
                const int* __restrict__ rec_dst, const float4* __restrict__ rec_u4,
                const float* __restrict__ rec_rbf,
                const float* __restrict__ phi,
                const unsigned* __restrict__ vPi, unsigned* __restrict__ vPo,
                float* __restrict__ s,
                ushort* __restrict__ catH, ushort* __restrict__ catL,
                const float* __restrict__ distW, const float* __restrict__ distb)
{
    const int tid    = threadIdx.x;
    const int slot   = tid >> 7;                // 0..3 within block
    const int f      = tid & 127;
    const int slot_g = blockIdx.x * 4 + slot;   // global slot id
    const int nslots = EDGE_BLOCKS * 4;         // 10000 slots, 2 atoms each

    // per-lane weight registers: k=20 is the bias row
    float wx[21], wy[21], wz[21];
#pragma unroll
    for (int k = 0; k < NRBF; ++k) {
        wx[k] = distW[k * 384 + f];
        wy[k] = distW[k * 384 + 128 + f];
        wz[k] = distW[k * 384 + 256 + f];
    }
    wx[20] = distb[f];
    wy[20] = distb[128 + f];
    wz[20] = distb[256 + f];
#pragma unroll
    for (int k = 0; k < 21; ++k) {
        asm volatile("" : "+v"(wx[k]), "+v"(wy[k]), "+v"(wz[k]));
    }

    for (int a = slot_g; a < N_ATOMS; a += nslots) {
        const int beg = rowptr[a];
        const int end = beg + deg[a];
        float s_acc = 0.f, vx = 0.f, vy = 0.f, vz = 0.f;

        for (int p = beg; p < end; p += 2) {
            const int  has2 = (p + 1 < end);
            const int  p1   = has2 ? p + 1 : p;
            const float m1  = has2 ? 1.f : 0.f;

            // headers (slot-uniform)
            float4 u40 = rec_u4[p];
            float4 u41 = rec_u4[p1];
            int dst0 = rec_dst[p];
            int dst1 = rec_dst[p1];

            // gathers for BOTH edges issued back-to-back (independent chains)
            const float* ph0 = phi + (size_t)dst0 * 384 + f;
            const float* ph1 = phi + (size_t)dst1 * 384 + f;
            float p00 = ph0[0], p01 = ph0[128], p02 = ph0[256];
            float p10 = ph1[0], p11 = ph1[128], p12 = ph1[256];
            size_t di0 = (size_t)dst0 * FEAT + f;
            size_t di1 = (size_t)dst1 * FEAT + f;
            float v0x = reconP(vPi[di0]);
            float v0y = reconP(vPi[PLANE + di0]);
            float v0z = reconP(vPi[2 * (size_t)PLANE + di0]);
            float v1x = reconP(vPi[di1]);
            float v1y = reconP(vPi[PLANE + di1]);
            float v1z = reconP(vPi[2 * (size_t)PLANE + di1]);
            const float4* rb0 = reinterpret_cast<const float4*>(rec_rbf + (size_t)p  * NRBF);
            const float4* rb1 = reinterpret_cast<const float4*>(rec_rbf + (size_t)p1 * NRBF);
            float4 a0 = rb0[0], a1 = rb0[1], a2 = rb0[2], a3 = rb0[3], a4 = rb0[4];
            float4 b0 = rb1[0], b1 = rb1[1], b2 = rb1[2], b3 = rb1[3], b4 = rb1[4];

            const float rr0[21] = {a0.x, a0.y, a0.z, a0.w, a1.x, a1.y, a1.z, a1.w,
                                   a2.x, a2.y, a2.z, a2.w, a3.x, a3.y, a3.z, a3.w,
                                   a4.x, a4.y, a4.z, a4.w, u40.w};
            const float rr1[21] = {b0.x, b0.y, b0.z, b0.w, b1.x, b1.y, b1.z, b1.w,
                                   b2.x, b2.y, b2.z, b2.w, b3.x, b3.y, b3.z, b3.w,
                                   b4.x, b4.y, b4.z, b4.w, u41.w};
            float w00 = 0.f, w01 = 0.f, w02 = 0.f;
            float w10 = 0.f, w11 = 0.f, w12 = 0.f;
#pragma unroll
            for (int k = 0; k < 21; ++k) {
                w00 += rr0[k] * wx[k];
                w01 += rr0[k] * wy[k];
                w02 += rr0[k] * wz[k];
                w10 += rr1[k] * wx[k];
                w11 += rr1[k] * wy[k];
                w12 += rr1[k] * wz[k];
            }
            float i00 = p00 * w00, i01 = p01 * w01, i02 = p02 * w02;
            float i10 = (p10 * w10) * m1, i11 = (p11 * w11) * m1, i12 = (p12 * w12) * m1;
            // sequential accumulation: e0 then e1 (order-preserving)
            vx += i02 * u40.x + i00 * v0x;
            vy += i02 * u40.y + i00 * v0y;
            vz += i02 * u40.z + i00 * v0z;
            s_acc += i01;
            vx += i12 * u41.x + i10 * v1x;
            vy += i12 * u41.y + i10 * v1y;
            vz += i12 * u41.z + i10 * v1z;
            s_acc += i11;
        }

        // epilogue: this slot's 128 lanes write atom a's outputs
        size_t si = (size_t)a * FEAT + f;
        float ns = s[si] + s_acc;
        s[si] = ns;
        float nx = reconP(vPi[si])                     + vx;
        float ny = reconP(vPi[PLANE + si])             + vy;
        float nz = reconP(vPi[2 * (size_t)PLANE + si]) + vz;
        vPo[si] = packP(nx);
        vPo[PLANE + si] = packP(ny);
        vPo[2 * (size_t)PLANE + si] = packP(nz);
        ushort h, l;
        split2(ns, h, l);
        catH[(size_t)a * 128 + f] = h;
        catL[(size_t)a * 128 + f] = l;
    }
}

// CG message; conv0 also scatters s (s_add path)
__global__ __launch_bounds__(128)
void k_cg_msg(const int* __restrict__ mapping, const float* __restrict__ phi_mid,
              const float* __restrict__ rbf_a, const float* __restrict__ env_a,
              const float* __restrict__ distW, const float* __restrict__ distb,
              const float* __restrict__ s_add, float* __restrict__ S_acc)
{
    int n = blockIdx.x;
    float env = env_a[n];
    int f = threadIdx.x;
    if (env == 0.f && s_add == nullptr) return;
    float val = s_add ? s_add[n * FEAT + f] : 0.f;
    if (env != 0.f) {
        __shared__ float sh_rbf[NRBF];
        if (f < NRBF) sh_rbf[f] = rbf_a[n * NRBF + f];
        __syncthreads();
        float w1 = 0.f;
#pragma unroll
        for (int k = 0; k < NRBF; ++k)
            w1 += sh_rbf[k] * distW[k * 384 + 128 + f];
        w1 += distb[128 + f] * env;
        val += phi_mid[n * FEAT + f] * w1;
    }
    atomicAdd(&S_acc[mapping[n] * FEAT + f], val);
}

__global__ void k_finalize(const float* __restrict__ S_acc, const float* __restrict__ cnt,
                           float* __restrict__ out, int add)
{
    int idx = blockIdx.x * blockDim.x + threadIdx.x;
    if (idx >= N_CG * FEAT) return;
    float val = S_acc[idx] / fmaxf(cnt[idx >> 7], 1.f);
    if (add) out[idx] += val;
    else     out[idx] = val;
}

// ---------------------------------------------------------------------------
extern "C" void kernel_launch(void* const* d_in, const int* in_sizes, int n_in,
                              void* d_out, int out_size, void* d_ws, size_t ws_size,
                              hipStream_t stream)
{
    const int*   z        = (const int*)d_in[0];
    const float* xyz      = (const float*)d_in[1];
    const float* cg_xyz   = (const float*)d_in[2];
    const int*   mapping  = (const int*)d_in[3];
    const int*   nbr      = (const int*)d_in[4];
    const float* embed    = (const float*)d_in[5];
    const float* msg_W1   = (const float*)d_in[6];
    const float* msg_b1   = (const float*)d_in[7];
    const float* msg_W2   = (const float*)d_in[8];
    const float* msg_b2   = (const float*)d_in[9];
    const float* msg_dW   = (const float*)d_in[10];
    const float* msg_db   = (const float*)d_in[11];
    const float* upd_U    = (const float*)d_in[12];
    const float* upd_V    = (const float*)d_in[13];
    const float* upd_W1   = (const float*)d_in[14];
    const float* upd_b1   = (const float*)d_in[15];
    const float* upd_W2   = (const float*)d_in[16];
    const float* upd_b2   = (const float*)d_in[17];
    const float* cg_W1    = (const float*)d_in[18];
    const float* cg_b1    = (const float*)d_in[19];
    const float* cg_W2    = (const float*)d_in[20];
    const float* cg_b2    = (const float*)d_in[21];
    const float* cg_dW    = (const float*)d_in[22];
    const float* cg_db    = (const float*)d_in[23];
    float* out = (float*)d_out;

    float* ws = (float*)d_ws;
    size_t o = 0;
    float* s      = ws + o; o += PLANE;
    float* uv     = ws + o; o += PLANE;                 // phi_mid scratch
    float* phi    = ws + o; o += (size_t)N_ATOMS * 384; // phi
    float* catpk  = ws + o; o += PLANE;                 // Ccat s-half hi+lo
    float* spk    = ws + o; o += PLANE;                 // packed s (initial only)
    unsigned* vPA = (unsigned*)(ws + o); o += 3 * PLANE; // packed v buffer A
    unsigned* vPB = (unsigned*)(ws + o); o += 3 * PLANE; // packed v buffer B
    float4* rec_u4 = (float4*)(ws + o); o += (size_t)N_EDGES * 4;
    float* rec_rbf = ws + o; o += (size_t)N_EDGES * NRBF;
    int*   rec_dst = (int*)(ws + o); o += N_EDGES;
    float* rbf_a  = ws + o; o += (size_t)N_ATOMS * NRBF;
    float* env_a  = ws + o; o += N_ATOMS;
    float* cnt    = ws + o; o += N_CG;
    float* S_acc  = ws + o; o += (size_t)NCONV * N_CG * FEAT;   // triple-buffered
    int*   deg    = (int*)(ws + o); o += N_ATOMS;
    int*   rowptr = (int*)(ws + o); o += N_ATOMS;
    int*   cursor = (int*)(ws + o); o += N_ATOMS;
    ushort* packH = (ushort*)(ws + o); o += (size_t)NCONV * PACK_PER_CONV / 2;
    ushort* packL = (ushort*)(ws + o); o += (size_t)NCONV * PACK_PER_CONV / 2;

    ushort* catH = (ushort*)catpk; ushort* catL = catH + (size_t)N_ATOMS * 128;
    ushort* sH = (ushort*)spk;  ushort* sL = sH + PLANE;

    // ---- setup ----
    hipMemsetAsync(vPA, 0, sizeof(unsigned) * 3 * PLANE, stream);  // v = 0
    hipMemsetAsync(cnt, 0, sizeof(float) * N_CG, stream);
    hipMemsetAsync(deg, 0, sizeof(int) * N_ATOMS, stream);
    hipMemsetAsync(cursor, 0, sizeof(int) * N_ATOMS, stream);
    hipMemsetAsync(S_acc, 0, sizeof(float) * NCONV * N_CG * FEAT, stream);
    k_pack_all<<<dim3(192, 8, 3), 256, 0, stream>>>(msg_W1, msg_W2, upd_V, upd_W1,
                                                    upd_W2, upd_U, cg_W1, cg_W2,
                                                    packH, packL);
    k_s_init<<<(PLANE + 255) / 256, 256, 0, stream>>>(z, embed, s, sH, sL);
    k_atom_geo<<<(N_ATOMS + 255) / 256, 256, 0, stream>>>(mapping, xyz, cg_xyz,
                                                          rbf_a, env_a, cnt);
    k_deg<<<(N_EDGES + 255) / 256, 256, 0, stream>>>(nbr, deg);
    k_scan<<<1, 1024, 0, stream>>>(deg, rowptr);
    k_fill<<<(N_EDGES + 255) / 256, 256, 0, stream>>>(nbr, xyz, rowptr, cursor,
                                                      rec_dst, rec_u4, rec_rbf);

    unsigned* vPc = vPA;    // current (gather source)
    unsigned* vPn = vPB;    // next (write target)

    // phi0 = msg MLP on the initial s
    mlp_fused<128, 384><<<625, 256, 0, stream>>>(
        sH, sL, packH + 0, packL + 0, msg_b1,
        packH + 16384, packL + 16384, msg_b2, 0, phi);

    for (int i = 0; i < NCONV; ++i) {
        const float* ub1 = upd_b1 + (size_t)i * FEAT;
        const float* ub2 = upd_b2 + (size_t)i * 384;
        const float* mdW = msg_dW + (size_t)i * NRBF * 384;
        const float* mdb = msg_db + (size_t)i * 384;
        const float* cb1 = cg_b1  + (size_t)i * FEAT;
        const float* cb2 = cg_b2  + (size_t)i * 384;
        const float* cdW = cg_dW  + (size_t)i * NRBF * 384;
        const float* cdb = cg_db  + (size_t)i * 384;
        const size_t pb  = (size_t)i * PACK_PER_CONV;
        float* Sa = S_acc + (size_t)i * N_CG * FEAT;

        k_edge_seg<<<EDGE_BLOCKS, 512, 0, stream>>>(rowptr, deg, rec_dst, rec_u4,
                                                    rec_rbf, phi, vPc, vPn, s,
                                                    catH, catL, mdW, mdb);

        // fused update block + dual MLP (next msg + this cg) on the new s
        if (i < NCONV - 1) {
            const size_t pn = (size_t)(i + 1) * PACK_PER_CONV;
            k_update_mega<1><<<625, 256, 0, stream>>>(
                vPn, catH, catL,
                packH + pb + 65536,  packL + pb + 65536,        // upd_V
                packH + pb + 81920,  packL + pb + 81920,        // upd_W1
                ub1,
                packH + pb + 114688, packL + pb + 114688,       // upd_W2
                ub2,
                packH + pb + 163840, packL + pb + 163840,       // upd_U
                s,
                packH + pn + 0,      packL + pn + 0,            // msg W1 (next)
                msg_b1 + (size_t)(i + 1) * FEAT,
                packH + pn + 16384,  packL + pn + 16384,        // msg W2 (next)
                msg_b2 + (size_t)(i + 1) * 384,
                packH + pb + 180224, packL + pb + 180224, cb1,  // cg W1
                packH + pb + 196608, packL + pb + 196608, cb2,  // cg W2 (mid)
                phi, uv);
        } else {
            k_update_mega<0><<<625, 256, 0, stream>>>(
                vPn, catH, catL,
                packH + pb + 65536,  packL + pb + 65536,
                packH + pb + 81920,  packL + pb + 81920,
                ub1,
                packH + pb + 114688, packL + pb + 114688,
                ub2,
                packH + pb + 163840, packL + pb + 163840,
                s,
                nullptr, nullptr, nullptr, nullptr, nullptr, nullptr,
                packH + pb + 180224, packL + pb + 180224, cb1,
                packH + pb + 196608, packL + pb + 196608, cb2,
                phi, uv);
        }

        k_cg_msg<<<N_ATOMS, 128, 0, stream>>>(mapping, uv, rbf_a, env_a, cdW, cdb,
                                              (i == 0) ? s : nullptr, Sa);
        k_finalize<<<(N_CG * FEAT + 255) / 256, 256, 0, stream>>>(Sa, cnt, out,
                                                                  i == 0 ? 0 : 1);

        // swap packed v buffers
        unsigned* t = vPn; vPn = vPc; vPc = t;
    }
}

// Round 9
// 1255.246 us; speedup vs baseline: 1.0463x; 1.0463x over previous
//
#include <hip/hip_runtime.h>
#include <math.h>

#define N_ATOMS 20000
#define N_CG    1000
#define N_EDGES 200000
#define FEAT    128
#define NRBF    20
#define NCONV   3
#define CUTOFF  5.0f
#define PLANE   (N_ATOMS * FEAT)      // 2,560,000
#define PI_F    3.14159265358979323846f
#define LDH     130                   // LDS H stride (f32) — bank-conflict-safe
#define SPAD    136                   // LDS ushort row stride (row = 272B -> 2-way alias, free)

#define PACK_PER_CONV 212992          // ushorts per conv in each of packH/packL

typedef __attribute__((ext_vector_type(8))) short bf16x8;
typedef __attribute__((ext_vector_type(4))) float f32x4;

__device__ __forceinline__ void split2(float x, ushort& h, ushort& l)
{
    unsigned u  = __float_as_uint(x);
    unsigned hb = (u + 0x7FFFu + ((u >> 16) & 1u)) & 0xFFFF0000u;
    float    hf = __uint_as_float(hb);
    float    lf = x - hf;                       // exact
    unsigned ul = __float_as_uint(lf);
    h = (ushort)(hb >> 16);
    l = (ushort)((ul + 0x7FFFu + ((ul >> 16) & 1u)) >> 16);
}

// interleaved packed v: one uint = (hi<<16)|lo; recon == hi-part + lo-part
__device__ __forceinline__ float reconP(unsigned u)
{
    return __uint_as_float(u & 0xFFFF0000u) + __uint_as_float(u << 16);
}

__device__ __forceinline__ unsigned packP(float x)
{
    ushort h, l;
    split2(x, h, l);
    return ((unsigned)h << 16) | l;
}

__device__ __forceinline__ void splitv8(const float* hv, bf16x8& ah, bf16x8& al)
{
#pragma unroll
    for (int j = 0; j < 8; ++j) {
        ushort h, l;
        split2(hv[j], h, l);
        ah[j] = (short)h; al[j] = (short)l;
    }
}

// unpack 8 interleaved uints -> hi/lo bf16x8 fragments
__device__ __forceinline__ void unpack8(const unsigned* __restrict__ p,
                                        bf16x8& ah, bf16x8& al)
{
#pragma unroll
    for (int j = 0; j < 8; ++j) {
        unsigned u = p[j];
        ah[j] = (short)(u >> 16);
        al[j] = (short)(u & 0xFFFFu);
    }
}

// 3-MFMA split product accumulate
#define MFMA3(ACC, AH_, AL_, BH_, BL_)                                              \
    ACC = __builtin_amdgcn_mfma_f32_16x16x32_bf16(AH_, BH_, ACC, 0, 0, 0);          \
    ACC = __builtin_amdgcn_mfma_f32_16x16x32_bf16(AH_, BL_, ACC, 0, 0, 0);          \
    ACC = __builtin_amdgcn_mfma_f32_16x16x32_bf16(AL_, BH_, ACC, 0, 0, 0);

// ---------------------------------------------------------------------------
// Fused MLP: C = (swish(A @ B1 + b1)) @ B2 + b2[bcol0:].  Used only for the
// initial phi0 (from k_s_init's packed s).
// ---------------------------------------------------------------------------
template<int K1, int N2>
__global__ __launch_bounds__(256)
void mlp_fused(const ushort* __restrict__ AH, const ushort* __restrict__ AL,
               const ushort* __restrict__ B1h, const ushort* __restrict__ B1l,
               const float* __restrict__ b1,
               const ushort* __restrict__ B2h, const ushort* __restrict__ B2l,
               const float* __restrict__ b2, int bcol0,
               float* __restrict__ C)
{
    __shared__ float Hs[32 * LDH];
    const int tid  = threadIdx.x;
    const int lane = tid & 63;
    const int w    = tid >> 6;
    const int wm   = w & 1, wn = w >> 1;
    const int m0   = blockIdx.x * 32;
    const int l15  = lane & 15;
    const int koff = (lane >> 4) * 8;
    const int rowb = wm * 16;                   // local row base
    const int q4   = (lane >> 4) * 4;

    // ---- phase 1: H = swish(A @ B1 + b1) (N1 = 128) ----
    f32x4 acc1[4];
#pragma unroll
    for (int j = 0; j < 4; ++j) acc1[j] = (f32x4){0.f, 0.f, 0.f, 0.f};
#pragma unroll
    for (int k0 = 0; k0 < K1; k0 += 32) {
        size_t aa = (size_t)(m0 + rowb + l15) * K1 + k0 + koff;
        bf16x8 ah = *reinterpret_cast<const bf16x8*>(AH + aa);
        bf16x8 al = *reinterpret_cast<const bf16x8*>(AL + aa);
#pragma unroll
        for (int nf = 0; nf < 4; ++nf) {
            size_t ba = (size_t)(wn * 64 + nf * 16 + l15) * K1 + k0 + koff;
            bf16x8 bh = *reinterpret_cast<const bf16x8*>(B1h + ba);
            bf16x8 bl = *reinterpret_cast<const bf16x8*>(B1l + ba);
            MFMA3(acc1[nf], ah, al, bh, bl);
        }
    }
#pragma unroll
    for (int nf = 0; nf < 4; ++nf) {
        int col = wn * 64 + nf * 16 + l15;
        float bv = b1[col];
#pragma unroll
        for (int r = 0; r < 4; ++r) {
            float x = acc1[nf][r] + bv;
            x = x / (1.f + __expf(-x));         // swish
            Hs[(rowb + q4 + r) * LDH + col] = x;
        }
    }
    __syncthreads();

    // ---- phase 2: C = H @ B2 + b2 ----
    constexpr int NF2  = N2 / 32;               // frags per wave
    constexpr int WCOL = N2 / 2;
    f32x4 acc2[NF2];
#pragma unroll
    for (int j = 0; j < NF2; ++j) acc2[j] = (f32x4){0.f, 0.f, 0.f, 0.f};
#pragma unroll
    for (int k0 = 0; k0 < 128; k0 += 32) {
        const float* hp = &Hs[(rowb + l15) * LDH + k0 + koff];
        float hv[8];
#pragma unroll
        for (int j = 0; j < 8; ++j) hv[j] = hp[j];
        bf16x8 ah, al;
        splitv8(hv, ah, al);
#pragma unroll
        for (int nf = 0; nf < NF2; ++nf) {
            size_t ba = (size_t)(wn * WCOL + nf * 16 + l15) * 128 + k0 + koff;
            bf16x8 bh = *reinterpret_cast<const bf16x8*>(B2h + ba);
            bf16x8 bl = *reinterpret_cast<const bf16x8*>(B2l + ba);
            MFMA3(acc2[nf], ah, al, bh, bl);
        }
    }
#pragma unroll
    for (int nf = 0; nf < NF2; ++nf) {
        int col = wn * WCOL + nf * 16 + l15;
        float bv = b2 ? b2[bcol0 + col] : 0.f;
#pragma unroll
        for (int r = 0; r < 4; ++r) {
            int row = m0 + rowb + q4 + r;
            C[(size_t)row * N2 + col] = acc2[nf][r] + bv;
        }
    }
}

// ---------------------------------------------------------------------------
// r9 MEGA kernel: same fusion as r8 (vnorm + stack-MLP + u/update + dual MLP)
// but 8-WAVE blocks (512 thr, 2 row-halves x 4 col-quarters).  r8 counters:
// MfmaUtil 6%, VALUBusy 8%, occupancy 9.5% — latency-bound with ~2 blk/CU
// (VGPR 180 capped 2 waves/SIMD).  Halving per-wave fragments drops VGPR
// under 128 (launch_bounds(512,4)) -> 2 blk/CU = 16 waves/CU.  k-loops
// unrolled; LDS ushort arrays padded to stride 136 (kills the 16-way
// ds_read_b128 row conflict: 1.68M/dispatch in r8).  Per-output math and
// k-order unchanged -> bit-identical results.
// ---------------------------------------------------------------------------
template<int HAS_MSG>
__global__ __launch_bounds__(512, 4)
void k_update_mega(unsigned* __restrict__ vP,
                   const ushort* __restrict__ catH, const ushort* __restrict__ catL,
                   const ushort* __restrict__ BVh, const ushort* __restrict__ BVl,
                   const ushort* __restrict__ W1h, const ushort* __restrict__ W1l,
                   const float*  __restrict__ b1,
                   const ushort* __restrict__ W2h, const ushort* __restrict__ W2l,
                   const float*  __restrict__ b2,
                   const ushort* __restrict__ BUh, const ushort* __restrict__ BUl,
                   float* __restrict__ s,
                   const ushort* __restrict__ M1h, const ushort* __restrict__ M1l,
                   const float*  __restrict__ m1b,
                   const ushort* __restrict__ M2h, const ushort* __restrict__ M2l,
                   const float*  __restrict__ m2b,
                   const ushort* __restrict__ C1h, const ushort* __restrict__ C1l,
                   const float*  __restrict__ c1b,
                   const ushort* __restrict__ C2h, const ushort* __restrict__ C2l,
                   const float*  __restrict__ c2b,      // full 384; cols 128.. used
                   float* __restrict__ phi, float* __restrict__ uv)
{
    // region0 Hs/Hm (16640B) | region1 nH,nL -> sHs,sLs (2*32*136*2 = 17408B)
    // | region2 Hc (16640B)  = 50688B
    __shared__ __align__(16) char smem[16640 + 17408 + 16640];
    float*  Hs  = (float*)smem;                          // region0 (also Hm)
    ushort* nH  = (ushort*)(smem + 16640);               // region1
    ushort* nL  = (ushort*)(smem + 16640 + 32 * SPAD * 2);
    ushort* sHs = nH;                                    // region1 reuse (post-B1)
    ushort* sLs = nL;
    float*  Hc  = (float*)(smem + 16640 + 17408);        // region2

    const int tid  = threadIdx.x;
    const int lane = tid & 63;
    const int w    = tid >> 6;                  // 0..7
    const int wm   = w & 1, wn = w >> 1;        // wn 0..3 (32-col quarter)
    const int m0   = blockIdx.x * 32;
    const int l15  = lane & 15;
    const int koff = (lane >> 4) * 8;
    const int rowb = wm * 16;
    const int q4   = (lane >> 4) * 4;

    // ---- phase A: dual GEMM (vv = v@V, uv = v@U) with a single A pass ----
    f32x4 accV[3][2], accU[3][2];
#pragma unroll
    for (int d = 0; d < 3; ++d)
#pragma unroll
        for (int j = 0; j < 2; ++j) {
            accV[d][j] = (f32x4){0.f, 0.f, 0.f, 0.f};
            accU[d][j] = (f32x4){0.f, 0.f, 0.f, 0.f};
        }
#pragma unroll
    for (int k0 = 0; k0 < 128; k0 += 32) {
        bf16x8 ah[3], al[3];
#pragma unroll
        for (int d = 0; d < 3; ++d) {
            size_t aa = (size_t)d * PLANE + (size_t)(m0 + rowb + l15) * 128 + k0 + koff;
            unsigned u[8];
#pragma unroll
            for (int j = 0; j < 8; ++j) u[j] = vP[aa + j];
            unpack8(u, ah[d], al[d]);
        }
#pragma unroll
        for (int nf = 0; nf < 2; ++nf) {
            size_t ba = (size_t)(wn * 32 + nf * 16 + l15) * 128 + k0 + koff;
            bf16x8 bvh = *reinterpret_cast<const bf16x8*>(BVh + ba);
            bf16x8 bvl = *reinterpret_cast<const bf16x8*>(BVl + ba);
            bf16x8 buh = *reinterpret_cast<const bf16x8*>(BUh + ba);
            bf16x8 bul = *reinterpret_cast<const bf16x8*>(BUl + ba);
#pragma unroll
            for (int d = 0; d < 3; ++d) {
                MFMA3(accV[d][nf], ah[d], al[d], bvh, bvl);
            }
#pragma unroll
            for (int d = 0; d < 3; ++d) {
                MFMA3(accU[d][nf], ah[d], al[d], buh, bul);
            }
        }
    }
    // norm -> LDS
#pragma unroll
    for (int nf = 0; nf < 2; ++nf) {
        int col = wn * 32 + nf * 16 + l15;
#pragma unroll
        for (int r = 0; r < 4; ++r) {
            int lrow = rowb + q4 + r;
            float x = accV[0][nf][r], y = accV[1][nf][r], z = accV[2][nf][r];
            float nrm = sqrtf(x * x + y * y + z * z + 3e-15f);
            ushort h, l;
            split2(nrm, h, l);
            nH[lrow * SPAD + col] = h;
            nL[lrow * SPAD + col] = l;
        }
    }
    __syncthreads();

    // ---- phase B1: H = swish([Ccat_s | norm] @ W1 + b1), K1 = 256 ----
    f32x4 acc1[2];
#pragma unroll
    for (int j = 0; j < 2; ++j) acc1[j] = (f32x4){0.f, 0.f, 0.f, 0.f};
#pragma unroll
    for (int k0 = 0; k0 < 256; k0 += 32) {
        bf16x8 ah, al;
        if (k0 < 128) {
            size_t aa = (size_t)(m0 + rowb + l15) * 128 + k0 + koff;
            ah = *reinterpret_cast<const bf16x8*>(catH + aa);
            al = *reinterpret_cast<const bf16x8*>(catL + aa);
        } else {
            int la = (rowb + l15) * SPAD + (k0 - 128) + koff;
            ah = *reinterpret_cast<const bf16x8*>(nH + la);
            al = *reinterpret_cast<const bf16x8*>(nL + la);
        }
#pragma unroll
        for (int nf = 0; nf < 2; ++nf) {
            size_t ba = (size_t)(wn * 32 + nf * 16 + l15) * 256 + k0 + koff;
            bf16x8 bh = *reinterpret_cast<const bf16x8*>(W1h + ba);
            bf16x8 bl = *reinterpret_cast<const bf16x8*>(W1l + ba);
            MFMA3(acc1[nf], ah, al, bh, bl);
        }
    }
#pragma unroll
    for (int nf = 0; nf < 2; ++nf) {
        int col = wn * 32 + nf * 16 + l15;
        float bv = b1[col];
#pragma unroll
        for (int r = 0; r < 4; ++r) {
            float x = acc1[nf][r] + bv;
            x = x / (1.f + __expf(-x));         // swish
            Hs[(rowb + q4 + r) * LDH + col] = x;
        }
    }
    __syncthreads();   // nH/nL reads done block-wide; region1 reusable below

    // ---- phase B2: stack fragments IN REGISTERS, wave-aligned to phase C ----
    // group g: 0=avv, 1=asv, 2=ass; col = g*128 + wn*32 + j*16 + l15
    f32x4 acc2[6];
#pragma unroll
    for (int j = 0; j < 6; ++j) acc2[j] = (f32x4){0.f, 0.f, 0.f, 0.f};
#pragma unroll
    for (int k0 = 0; k0 < 128; k0 += 32) {
        const float* hp = &Hs[(rowb + l15) * LDH + k0 + koff];
        float hv[8];
#pragma unroll
        for (int j = 0; j < 8; ++j) hv[j] = hp[j];
        bf16x8 ah, al;
        splitv8(hv, ah, al);
#pragma unroll
        for (int g = 0; g < 3; ++g) {
#pragma unroll
            for (int j = 0; j < 2; ++j) {
                size_t ba = (size_t)(g * 128 + wn * 32 + j * 16 + l15) * 128 + k0 + koff;
                bf16x8 bh = *reinterpret_cast<const bf16x8*>(W2h + ba);
                bf16x8 bl = *reinterpret_cast<const bf16x8*>(W2l + ba);
                MFMA3(acc2[g * 2 + j], ah, al, bh, bl);
            }
        }
    }

    // ---- phase C: update rule; new packed s goes to LDS (region1) ----
#pragma unroll
    for (int nf = 0; nf < 2; ++nf) {
        int col = wn * 32 + nf * 16 + l15;
        float bavv = b2[col];
        float basv = b2[128 + col];
        float bass = b2[256 + col];
#pragma unroll
        for (int r = 0; r < 4; ++r) {
            int lrow = rowb + q4 + r;
            int row  = m0 + lrow;
            size_t idx = (size_t)row * FEAT + col;
            float avv = acc2[nf][r]     + bavv;
            float asv = acc2[2 + nf][r] + basv;
            float ass = acc2[4 + nf][r] + bass;
            float u0 = accU[0][nf][r], u1 = accU[1][nf][r], u2 = accU[2][nf][r];
            float w0 = accV[0][nf][r], w1 = accV[1][nf][r], w2 = accV[2][nf][r];
            float dot = u0 * w0 + u1 * w1 + u2 * w2;
            float n0 = reconP(vP[idx])                      + u0 * avv;
            float n1 = reconP(vP[PLANE + idx])              + u1 * avv;
            float n2 = reconP(vP[2 * (size_t)PLANE + idx])  + u2 * avv;
            vP[idx] = packP(n0);
            vP[PLANE + idx] = packP(n1);
            vP[2 * (size_t)PLANE + idx] = packP(n2);
            float ns = s[idx] + dot * asv + ass;
            s[idx] = ns;
            ushort h, l;
            split2(ns, h, l);
            sHs[lrow * SPAD + col] = h;
            sLs[lrow * SPAD + col] = l;
        }
    }
    __syncthreads();

    // ---- phase D1: hidden layers of msg (next conv) and cg MLPs from LDS s ----
    f32x4 am[2], ac[2];
#pragma unroll
    for (int j = 0; j < 2; ++j) {
        am[j] = (f32x4){0.f, 0.f, 0.f, 0.f};
        ac[j] = (f32x4){0.f, 0.f, 0.f, 0.f};
    }
#pragma unroll
    for (int k0 = 0; k0 < 128; k0 += 32) {
        int la = (rowb + l15) * SPAD + k0 + koff;
        bf16x8 ah = *reinterpret_cast<const bf16x8*>(sHs + la);
        bf16x8 al = *reinterpret_cast<const bf16x8*>(sLs + la);
#pragma unroll
        for (int nf = 0; nf < 2; ++nf) {
            size_t ba = (size_t)(wn * 32 + nf * 16 + l15) * 128 + k0 + koff;
            if (HAS_MSG) {
                bf16x8 bh = *reinterpret_cast<const bf16x8*>(M1h + ba);
                bf16x8 bl = *reinterpret_cast<const bf16x8*>(M1l + ba);
                MFMA3(am[nf], ah, al, bh, bl);
            }
            bf16x8 ch = *reinterpret_cast<const bf16x8*>(C1h + ba);
            bf16x8 cl = *reinterpret_cast<const bf16x8*>(C1l + ba);
            MFMA3(ac[nf], ah, al, ch, cl);
        }
    }
#pragma unroll
    for (int nf = 0; nf < 2; ++nf) {
        int col = wn * 32 + nf * 16 + l15;
        float bvc = c1b[col];
        float bvm = HAS_MSG ? m1b[col] : 0.f;
#pragma unroll
        for (int r = 0; r < 4; ++r) {
            int lr = rowb + q4 + r;
            if (HAS_MSG) {
                float x = am[nf][r] + bvm;
                Hs[lr * LDH + col] = x / (1.f + __expf(-x));   // Hm (region0)
            }
            float y = ac[nf][r] + bvc;
            Hc[lr * LDH + col] = y / (1.f + __expf(-y));
        }
    }
    __syncthreads();

    // ---- phase D2: phi (384, msg; 96 cols/wave) and uv (128, cg) ----
    f32x4 a2m[6], a2c[2];
    if (HAS_MSG) {
#pragma unroll
        for (int j = 0; j < 6; ++j) a2m[j] = (f32x4){0.f, 0.f, 0.f, 0.f};
    }
#pragma unroll
    for (int j = 0; j < 2; ++j)  a2c[j] = (f32x4){0.f, 0.f, 0.f, 0.f};
#pragma unroll
    for (int k0 = 0; k0 < 128; k0 += 32) {
        const float* hpc = &Hc[(rowb + l15) * LDH + k0 + koff];
        float hvc[8];
#pragma unroll
        for (int j = 0; j < 8; ++j) hvc[j] = hpc[j];
        bf16x8 ahc, alc;
        splitv8(hvc, ahc, alc);
#pragma unroll
        for (int nf = 0; nf < 2; ++nf) {
            size_t ba = (size_t)(wn * 32 + nf * 16 + l15) * 128 + k0 + koff;
            bf16x8 bh = *reinterpret_cast<const bf16x8*>(C2h + ba);
            bf16x8 bl = *reinterpret_cast<const bf16x8*>(C2l + ba);
            MFMA3(a2c[nf], ahc, alc, bh, bl);
        }
        if (HAS_MSG) {
            const float* hpm = &Hs[(rowb + l15) * LDH + k0 + koff];
            float hvm[8];
#pragma unroll
            for (int j = 0; j < 8; ++j) hvm[j] = hpm[j];
            bf16x8 ahm, alm;
            splitv8(hvm, ahm, alm);
#pragma unroll
            for (int nf = 0; nf < 6; ++nf) {
                size_t ba = (size_t)(wn * 96 + nf * 16 + l15) * 128 + k0 + koff;
                bf16x8 bh = *reinterpret_cast<const bf16x8*>(M2h + ba);
                bf16x8 bl = *reinterpret_cast<const bf16x8*>(M2l + ba);
                MFMA3(a2m[nf], ahm, alm, bh, bl);
            }
        }
    }
    if (HAS_MSG) {
#pragma unroll
        for (int nf = 0; nf < 6; ++nf) {
            int col = wn * 96 + nf * 16 + l15;
            float bv = m2b[col];
#pragma unroll
            for (int r = 0; r < 4; ++r) {
                int row = m0 + rowb + q4 + r;
                phi[(size_t)row * 384 + col] = a2m[nf][r] + bv;
            }
        }
    }
#pragma unroll
    for (int nf = 0; nf < 2; ++nf) {
        int col = wn * 32 + nf * 16 + l15;
        float bv = c2b[128 + col];
#pragma unroll
        for (int r = 0; r < 4; ++r) {
            int row = m0 + rowb + q4 + r;
            uv[(size_t)row * 128 + col] = a2c[nf][r] + bv;
        }
    }
}

// ---------------------------------------------------------------------------
// Weight pre-pack: fp32 W[k][col0+n] -> bf16 hi/lo at [n][k] (k-contiguous).
// ---------------------------------------------------------------------------
__global__ void k_pack_all(const float* __restrict__ msg_W1, const float* __restrict__ msg_W2,
                           const float* __restrict__ upd_V,  const float* __restrict__ upd_W1,
                           const float* __restrict__ upd_W2, const float* __restrict__ upd_U,
                           const float* __restrict__ cg_W1,  const float* __restrict__ cg_W2,
                           ushort* __restrict__ Bh, ushort* __restrict__ Bl)
{
    const int wid = blockIdx.y, conv = blockIdx.z;
    const float* W; int K, N, ldw, col0; size_t off;
    switch (wid) {
        case 0: W = msg_W1 + (size_t)conv * 16384; K = 128; N = 128; ldw = 128; col0 = 0;   off = 0;      break;
        case 1: W = msg_W2 + (size_t)conv * 49152; K = 128; N = 384; ldw = 384; col0 = 0;   off = 16384;  break;
        case 2: W = upd_V  + (size_t)conv * 16384; K = 128; N = 128; ldw = 128; col0 = 0;   off = 65536;  break;
        case 3: W = upd_W1 + (size_t)conv * 32768; K = 256; N = 128; ldw = 128; col0 = 0;   off = 81920;  break;
        case 4: W = upd_W2 + (size_t)conv * 49152; K = 128; N = 384; ldw = 384; col0 = 0;   off = 114688; break;
        case 5: W = upd_U  + (size_t)conv * 16384; K = 128; N = 128; ldw = 128; col0 = 0;   off = 163840; break;
        case 6: W = cg_W1  + (size_t)conv * 16384; K = 128; N = 128; ldw = 128; col0 = 0;   off = 180224; break;
        default:W = cg_W2  + (size_t)conv * 49152; K = 128; N = 128; ldw = 384; col0 = 128; off = 196608; break;
    }
    off += (size_t)conv * PACK_PER_CONV;
    int idx = blockIdx.x * 256 + threadIdx.x;
    if (idx >= K * N) return;
    int k = idx & (K - 1);
    int n = idx >> ((K == 256) ? 8 : 7);
    ushort h, l;
    split2(W[(size_t)k * ldw + col0 + n], h, l);
    Bh[off + (size_t)n * K + k] = h;
    Bl[off + (size_t)n * K + k] = l;
}

// ---------------------------------------------------------------------------
// Setup kernels
// ---------------------------------------------------------------------------
__global__ void k_s_init(const int* __restrict__ z, const float* __restrict__ embed,
                         float* __restrict__ s, ushort* __restrict__ sH, ushort* __restrict__ sL)
{
    int idx = blockIdx.x * blockDim.x + threadIdx.x;
    if (idx >= PLANE) return;
    int n = idx >> 7, g = idx & 127;
    float e = embed[z[n] * FEAT + g];
    s[idx] = e;
    ushort h, l;
    split2(e, h, l);
    sH[idx] = h; sL[idx] = l;
}

__global__ void k_atom_geo(const int* __restrict__ mapping,
                           const float* __restrict__ xyz, const float* __restrict__ cg_xyz,
                           float* __restrict__ rbf_a, float* __restrict__ env_a,
                           float* __restrict__ cnt)
{
    int n = blockIdx.x * blockDim.x + threadIdx.x;
    if (n >= N_ATOMS) return;
    int m = mapping[n];
    float dx = xyz[n * 3 + 0] - cg_xyz[m * 3 + 0];
    float dy = xyz[n * 3 + 1] - cg_xyz[m * 3 + 1];
    float dz = xyz[n * 3 + 2] - cg_xyz[m * 3 + 2];
    float d = sqrtf(dx * dx + dy * dy + dz * dz + 3e-15f);
    float env = (d < CUTOFF) ? 0.5f * (cosf(PI_F * d / CUTOFF) + 1.f) : 0.f;
    env_a[n] = env;
    float s = env / d;
#pragma unroll
    for (int k = 0; k < NRBF; ++k)
        rbf_a[n * NRBF + k] = sinf((k + 1) * PI_F * d / CUTOFF) * s;
    atomicAdd(&cnt[m], 1.f);
}

// ---------------------------------------------------------------------------
// CSR build
// ---------------------------------------------------------------------------
__global__ void k_deg(const int* __restrict__ nbr, int* __restrict__ deg)
{
    int e = blockIdx.x * blockDim.x + threadIdx.x;
    if (e < N_EDGES) atomicAdd(&deg[nbr[2 * e]], 1);
}

__global__ __launch_bounds__(1024)
void k_scan(const int* __restrict__ deg, int* __restrict__ rowptr)
{
    __shared__ int sh[1024];
    const int chunk = (N_ATOMS + 1023) / 1024;
    int t = threadIdx.x;
    int base = t * chunk;
    int sum = 0;
    for (int i = 0; i < chunk; ++i) {
        int idx = base + i;
        if (idx < N_ATOMS) sum += deg[idx];
    }
    sh[t] = sum;
    __syncthreads();
    for (int off = 1; off < 1024; off <<= 1) {
        int val = (t >= off) ? sh[t - off] : 0;
        __syncthreads();
        sh[t] += val;
        __syncthreads();
    }
    int run = (t == 0) ? 0 : sh[t - 1];
    for (int i = 0; i < chunk; ++i) {
        int idx = base + i;
        if (idx < N_ATOMS) { rowptr[idx] = run; run += deg[idx]; }
    }
}

__global__ void k_fill(const int* __restrict__ nbr, const float* __restrict__ xyz,
                       const int* __restrict__ rowptr, int* __restrict__ cursor,
                       int* __restrict__ rec_dst, float4* __restrict__ rec_u4,
                       float* __restrict__ rec_rbf)
{
    int e = blockIdx.x * blockDim.x + threadIdx.x;
    if (e >= N_EDGES) return;
    int src = nbr[2 * e], dst = nbr[2 * e + 1];
    int pos = atomicAdd(&cursor[src], 1);
    int q = rowptr[src] + pos;
    float dx = xyz[dst * 3 + 0] - xyz[src * 3 + 0];
    float dy = xyz[dst * 3 + 1] - xyz[src * 3 + 1];
    float dz = xyz[dst * 3 + 2] - xyz[src * 3 + 2];
    float d = sqrtf(dx * dx + dy * dy + dz * dz + 3e-15f);
    float env = (d < CUTOFF) ? 0.5f * (cosf(PI_F * d / CUTOFF) + 1.f) : 0.f;
    rec_dst[q] = dst;
    rec_u4[q] = make_float4(dx / d, dy / d, dz / d, env);
    float sc = env / d;
#pragma unroll
    for (int k = 0; k < NRBF; ++k)
        rec_rbf[(size_t)q * NRBF + k] = sinf((k + 1) * PI_F * d / CUTOFF) * sc;
}

// ---------------------------------------------------------------------------
// Edge segment-sum (r2 slot-per-atom, r4 2-edge ILP, r6 interleaved packed v).
// At its memory-path floor (~313 MB L2-miss stream, invariant r0-r8).
// ---------------------------------------------------------------------------
#define EDGE_BLOCKS 2500
__global__ __launch_bounds__(512, 2)
void k_edge_seg(const int* __restrict__ rowptr, const int* __restrict__ deg,
                const int* __restrict__ rec_dst, const float4* __restrict__ rec_u4,
                const float* __restrict__ rec_rbf,
                const float* __restrict__ phi,
                const unsigned* __restrict__ vPi, unsigned* __restrict__ vPo,
                float* __restrict__ s,
                ushort* __restrict__ catH, ushort* __restrict__ catL,
                const float* __restrict__ distW, const float* __restrict__ distb)
{
    const int tid    = threadIdx.x;
    const int slot   = tid >> 7;                // 0..3 within block
    const int f      = tid & 127;
    const int slot_g = blockIdx.x * 4 + slot;   // global slot id
    const int nslots = EDGE_BLOCKS * 4;         // 10000 slots, 2 atoms each

    // per-lane weight registers: k=20 is the bias row
    float wx[21], wy[21], wz[21];
#pragma unroll
    for (int k = 0; k < NRBF; ++k) {
        wx[k] = distW[k * 384 + f];
        wy[k] = distW[k * 384 + 128 + f];
        wz[k] = distW[k * 384 + 256 + f];
    }
    wx[20] = distb[f];
    wy[20] = distb[128 + f];
    wz[20] = distb[256 + f];
#pragma unroll
    for (int k = 0; k < 21; ++k) {
        asm volatile("" : "+v"(wx[k]), "+v"(wy[k]), "+v"(wz[k]));
    }

    for (int a = slot_g; a < N_ATOMS; a += nslots) {
        const int beg = rowptr[a];
        const int end = beg + deg[a];
        float s_acc = 0.f, vx = 0.f, vy = 0.f, vz = 0.f;

        for (int p = beg; p < end; p += 2) {
            const int  has2 = (p + 1 < end);
            const int  p1   = has2 ? p + 1 : p;
            const float m1  = has2 ? 1.f : 0.f;

            // headers (slot-uniform)
            float4 u40 = rec_u4[p];
            float4 u41 = rec_u4[p1];
            int dst0 = rec_dst[p];
            int dst1 = rec_dst[p1];

            // gathers for BOTH edges issued back-to-back (independent chains)
            const float* ph0 = phi + (size_t)dst0 * 384 + f;
            const float* ph1 = phi + (size_t)dst1 * 384 + f;
            float p00 = ph0[0], p01 = ph0[128], p02 = ph0[256];
            float p10 = ph1[0], p11 = ph1[128], p12 = ph1[256];
            size_t di0 = (size_t)dst0 * FEAT + f;
            size_t di1 = (size_t)dst1 * FEAT + f;
            float v0x = reconP(vPi[di0]);
            float v0y = reconP(vPi[PLANE + di0]);
            float v0z = reconP(vPi[2 * (size_t)PLANE + di0]);
            float v1x = reconP(vPi[di1]);
            float v1y = reconP(vPi[PLANE + di1]);
            float v1z = reconP(vPi[2 * (size_t)PLANE + di1]);
            const float4* rb0 = reinterpret_cast<const float4*>(rec_rbf + (size_t)p  * NRBF);
            const float4* rb1 = reinterpret_cast<const float4*>(rec_rbf + (size_t)p1 * NRBF);
            float4 a0 = rb0[0], a1 = rb0[1], a2 = rb0[2], a3 = rb0[3], a4 = rb0[4];
            float4 b0 = rb1[0], b1 = rb1[1], b2 = rb1[2], b3 = rb1[3], b4 = rb1[4];

            const float rr0[21] = {a0.x, a0.y, a0.z, a0.w, a1.x, a1.y, a1.z, a1.w,
                                   a2.x, a2.y, a2.z, a2.w, a3.x, a3.y, a3.z, a3.w,
                                   a4.x, a4.y, a4.z, a4.w, u40.w};
            const float rr1[21] = {b0.x, b0.y, b0.z, b0.w, b1.x, b1.y, b1.z, b1.w,
                                   b2.x, b2.y, b2.z, b2.w, b3.x, b3.y, b3.z, b3.w,
                                   b4.x, b4.y, b4.z, b4.w, u41.w};
            float w00 = 0.f, w01 = 0.f, w02 = 0.f;
            float w10 = 0.f, w11 = 0.f, w12 = 0.f;
#pragma unroll
            for (int k = 0; k < 21; ++k) {
                w00 += rr0[k] * wx[k];
                w01 += rr0[k] * wy[k];
                w02 += rr0[k] * wz[k];
                w10 += rr1[k] * wx[k];
                w11 += rr1[k] * wy[k];
                w12 += rr1[k] * wz[k];
            }
            float i00 = p00 * w00, i01 = p01 * w01, i02 = p02 * w02;
            float i10 = (p10 * w10) * m1, i11 = (p11 * w11) * m1, i12 = (p12 * w12) * m1;
            // sequential accumulation: e0 then e1 (order-preserving)
            vx += i02 * u40.x + i00 * v0x;
            vy += i02 * u40.y + i00 * v0y;
            vz += i02 * u40.z + i00 * v0z;
            s_acc += i01;
            vx += i12 * u41.x + i10 * v1x;
            vy += i12 * u41.y + i10 * v1y;
            vz += i12 * u41.z + i10 * v1z;
            s_acc += i11;
        }

        // epilogue: this slot's 128 lanes write atom a's outputs
        size_t si = (size_t)a * FEAT + f;
        float ns = s[si] + s_acc;
        s[si] = ns;
        float nx = reconP(vPi[si])                     + vx;
        float ny = reconP(vPi[PLANE + si])             + vy;
        float nz = reconP(vPi[2 * (size_t)PLANE + si]) + vz;
        vPo[si] = packP(nx);
        vPo[PLANE + si] = packP(ny);
        vPo[2 * (size_t)PLANE + si] = packP(nz);
        ushort h, l;
        split2(ns, h, l);
        catH[(size_t)a * 128 + f] = h;
        catL[(size_t)a * 128 + f] = l;
    }
}

// CG message; conv0 also scatters s (s_add path)
__global__ __launch_bounds__(128)
void k_cg_msg(const int* __restrict__ mapping, const float* __restrict__ phi_mid,
              const float* __restrict__ rbf_a, const float* __restrict__ env_a,
              const float* __restrict__ distW, const float* __restrict__ distb,
              const float* __restrict__ s_add, float* __restrict__ S_acc)
{
    int n = blockIdx.x;
    float env = env_a[n];
    int f = threadIdx.x;
    if (env == 0.f && s_add == nullptr) return;
    float val = s_add ? s_add[n * FEAT + f] : 0.f;
    if (env != 0.f) {
        __shared__ float sh_rbf[NRBF];
        if (f < NRBF) sh_rbf[f] = rbf_a[n * NRBF + f];
        __syncthreads();
        float w1 = 0.f;
#pragma unroll
        for (int k = 0; k < NRBF; ++k)
            w1 += sh_rbf[k] * distW[k * 384 + 128 + f];
        w1 += distb[128 + f] * env;
        val += phi_mid[n * FEAT + f] * w1;
    }
    atomicAdd(&S_acc[mapping[n] * FEAT + f], val);
}

__global__ void k_finalize(const float* __restrict__ S_acc, const float* __restrict__ cnt,
                           float* __restrict__ out, int add)
{
    int idx = blockIdx.x * blockDim.x + threadIdx.x;
    if (idx >= N_CG * FEAT) return;
    float val = S_acc[idx] / fmaxf(cnt[idx >> 7], 1.f);
    if (add) out[idx] += val;
    else     out[idx] = val;
}

// ---------------------------------------------------------------------------
extern "C" void kernel_launch(void* const* d_in, const int* in_sizes, int n_in,
                              void* d_out, int out_size, void* d_ws, size_t ws_size,
                              hipStream_t stream)
{
    const int*   z        = (const int*)d_in[0];
    const float* xyz      = (const float*)d_in[1];
    const float* cg_xyz   = (const float*)d_in[2];
    const int*   mapping  = (const int*)d_in[3];
    const int*   nbr      = (const int*)d_in[4];
    const float* embed    = (const float*)d_in[5];
    const float* msg_W1   = (const float*)d_in[6];
    const float* msg_b1   = (const float*)d_in[7];
    const float* msg_W2   = (const float*)d_in[8];
    const float* msg_b2   = (const float*)d_in[9];
    const float* msg_dW   = (const float*)d_in[10];
    const float* msg_db   = (const float*)d_in[11];
    const float* upd_U    = (const float*)d_in[12];
    const float* upd_V    = (const float*)d_in[13];
    const float* upd_W1   = (const float*)d_in[14];
    const float* upd_b1   = (const float*)d_in[15];
    const float* upd_W2   = (const float*)d_in[16];
    const float* upd_b2   = (const float*)d_in[17];
    const float* cg_W1    = (const float*)d_in[18];
    const float* cg_b1    = (const float*)d_in[19];
    const float* cg_W2    = (const float*)d_in[20];
    const float* cg_b2    = (const float*)d_in[21];
    const float* cg_dW    = (const float*)d_in[22];
    const float* cg_db    = (const float*)d_in[23];
    float* out = (float*)d_out;

    float* ws = (float*)d_ws;
    size_t o = 0;
    float* s      = ws + o; o += PLANE;
    float* uv     = ws + o; o += PLANE;                 // phi_mid scratch
    float* phi    = ws + o; o += (size_t)N_ATOMS * 384; // phi
    float* catpk  = ws + o; o += PLANE;                 // Ccat s-half hi+lo
    float* spk    = ws + o; o += PLANE;                 // packed s (initial only)
    unsigned* vPA = (unsigned*)(ws + o); o += 3 * PLANE; // packed v buffer A
    unsigned* vPB = (unsigned*)(ws + o); o += 3 * PLANE; // packed v buffer B
    float4* rec_u4 = (float4*)(ws + o); o += (size_t)N_EDGES * 4;
    float* rec_rbf = ws + o; o += (size_t)N_EDGES * NRBF;
    int*   rec_dst = (int*)(ws + o); o += N_EDGES;
    float* rbf_a  = ws + o; o += (size_t)N_ATOMS * NRBF;
    float* env_a  = ws + o; o += N_ATOMS;
    float* cnt    = ws + o; o += N_CG;
    float* S_acc  = ws + o; o += (size_t)NCONV * N_CG * FEAT;   // triple-buffered
    int*   deg    = (int*)(ws + o); o += N_ATOMS;
    int*   rowptr = (int*)(ws + o); o += N_ATOMS;
    int*   cursor = (int*)(ws + o); o += N_ATOMS;
    ushort* packH = (ushort*)(ws + o); o += (size_t)NCONV * PACK_PER_CONV / 2;
    ushort* packL = (ushort*)(ws + o); o += (size_t)NCONV * PACK_PER_CONV / 2;

    ushort* catH = (ushort*)catpk; ushort* catL = catH + (size_t)N_ATOMS * 128;
    ushort* sH = (ushort*)spk;  ushort* sL = sH + PLANE;

    // ---- setup ----
    hipMemsetAsync(vPA, 0, sizeof(unsigned) * 3 * PLANE, stream);  // v = 0
    hipMemsetAsync(cnt, 0, sizeof(float) * N_CG, stream);
    hipMemsetAsync(deg, 0, sizeof(int) * N_ATOMS, stream);
    hipMemsetAsync(cursor, 0, sizeof(int) * N_ATOMS, stream);
    hipMemsetAsync(S_acc, 0, sizeof(float) * NCONV * N_CG * FEAT, stream);
    k_pack_all<<<dim3(192, 8, 3), 256, 0, stream>>>(msg_W1, msg_W2, upd_V, upd_W1,
                                                    upd_W2, upd_U, cg_W1, cg_W2,
                                                    packH, packL);
    k_s_init<<<(PLANE + 255) / 256, 256, 0, stream>>>(z, embed, s, sH, sL);
    k_atom_geo<<<(N_ATOMS + 255) / 256, 256, 0, stream>>>(mapping, xyz, cg_xyz,
                                                          rbf_a, env_a, cnt);
    k_deg<<<(N_EDGES + 255) / 256, 256, 0, stream>>>(nbr, deg);
    k_scan<<<1, 1024, 0, stream>>>(deg, rowptr);
    k_fill<<<(N_EDGES + 255) / 256, 256, 0, stream>>>(nbr, xyz, rowptr, cursor,
                                                      rec_dst, rec_u4, rec_rbf);

    unsigned* vPc = vPA;    // current (gather source)
    unsigned* vPn = vPB;    // next (write target)

    // phi0 = msg MLP on the initial s
    mlp_fused<128, 384><<<625, 256, 0, stream>>>(
        sH, sL, packH + 0, packL + 0, msg_b1,
        packH + 16384, packL + 16384, msg_b2, 0, phi);

    for (int i = 0; i < NCONV; ++i) {
        const float* ub1 = upd_b1 + (size_t)i * FEAT;
        const float* ub2 = upd_b2 + (size_t)i * 384;
        const float* mdW = msg_dW + (size_t)i * NRBF * 384;
        const float* mdb = msg_db + (size_t)i * 384;
        const float* cb1 = cg_b1  + (size_t)i * FEAT;
        const float* cb2 = cg_b2  + (size_t)i * 384;
        const float* cdW = cg_dW  + (size_t)i * NRBF * 384;
        const float* cdb = cg_db  + (size_t)i * 384;
        const size_t pb  = (size_t)i * PACK_PER_CONV;
        float* Sa = S_acc + (size_t)i * N_CG * FEAT;

        k_edge_seg<<<EDGE_BLOCKS, 512, 0, stream>>>(rowptr, deg, rec_dst, rec_u4,
                                                    rec_rbf, phi, vPc, vPn, s,
                                                    catH, catL, mdW, mdb);

        // fused update block + dual MLP (next msg + this cg) on the new s
        if (i < NCONV - 1) {
            const size_t pn = (size_t)(i + 1) * PACK_PER_CONV;
            k_update_mega<1><<<625, 512, 0, stream>>>(
                vPn, catH, catL,
                packH + pb + 65536,  packL + pb + 65536,        // upd_V
                packH + pb + 81920,  packL + pb + 81920,        // upd_W1
                ub1,
                packH + pb + 114688, packL + pb + 114688,       // upd_W2
                ub2,
                packH + pb + 163840, packL + pb + 163840,       // upd_U
                s,
                packH + pn + 0,      packL + pn + 0,            // msg W1 (next)
                msg_b1 + (size_t)(i + 1) * FEAT,
                packH + pn + 16384,  packL + pn + 16384,        // msg W2 (next)
                msg_b2 + (size_t)(i + 1) * 384,
                packH + pb + 180224, packL + pb + 180224, cb1,  // cg W1
                packH + pb + 196608, packL + pb + 196608, cb2,  // cg W2 (mid)
                phi, uv);
        } else {
            k_update_mega<0><<<625, 512, 0, stream>>>(
                vPn, catH, catL,
                packH + pb + 65536,  packL + pb + 65536,
                packH + pb + 81920,  packL + pb + 81920,
                ub1,
                packH + pb + 114688, packL + pb + 114688,
                ub2,
                packH + pb + 163840, packL + pb + 163840,
                s,
                nullptr, nullptr, nullptr, nullptr, nullptr, nullptr,
                packH + pb + 180224, packL + pb + 180224, cb1,
                packH + pb + 196608, packL + pb + 196608, cb2,
                phi, uv);
        }

        k_cg_msg<<<N_ATOMS, 128, 0, stream>>>(mapping, uv, rbf_a, env_a, cdW, cdb,
                                              (i == 0) ? s : nullptr, Sa);
        k_finalize<<<(N_CG * FEAT + 255) / 256, 256, 0, stream>>>(Sa, cnt, out,
                                                                  i == 0 ? 0 : 1);

        // swap packed v buffers
        unsigned* t = vPn; vPn = vPc; vPc = t;
    }
}

// Round 10
// 1237.195 us; speedup vs baseline: 1.0616x; 1.0146x over previous
//
#include <hip/hip_runtime.h>
#include <math.h>

#define N_ATOMS 20000
#define N_CG    1000
#define N_EDGES 200000
#define FEAT    128
#define NRBF    20
#define NCONV   3
#define CUTOFF  5.0f
#define PLANE   (N_ATOMS * FEAT)      // 2,560,000
#define PI_F    3.14159265358979323846f
#define LDH     130                   // LDS H stride (f32) — bank-conflict-safe
#define SPAD    136                   // LDS ushort row stride (row = 272B -> 2-way alias, free)

#define PACK_PER_CONV 212992          // ushorts per conv in each of packH/packL

typedef __attribute__((ext_vector_type(8))) short bf16x8;
typedef __attribute__((ext_vector_type(4))) float f32x4;

__device__ __forceinline__ void split2(float x, ushort& h, ushort& l)
{
    unsigned u  = __float_as_uint(x);
    unsigned hb = (u + 0x7FFFu + ((u >> 16) & 1u)) & 0xFFFF0000u;
    float    hf = __uint_as_float(hb);
    float    lf = x - hf;                       // exact
    unsigned ul = __float_as_uint(lf);
    h = (ushort)(hb >> 16);
    l = (ushort)((ul + 0x7FFFu + ((ul >> 16) & 1u)) >> 16);
}

// interleaved packed v: one uint = (hi<<16)|lo; recon == hi-part + lo-part
__device__ __forceinline__ float reconP(unsigned u)
{
    return __uint_as_float(u & 0xFFFF0000u) + __uint_as_float(u << 16);
}

__device__ __forceinline__ unsigned packP(float x)
{
    ushort h, l;
    split2(x, h, l);
    return ((unsigned)h << 16) | l;
}

__device__ __forceinline__ void splitv8(const float* hv, bf16x8& ah, bf16x8& al)
{
#pragma unroll
    for (int j = 0; j < 8; ++j) {
        ushort h, l;
        split2(hv[j], h, l);
        ah[j] = (short)h; al[j] = (short)l;
    }
}

// unpack 8 interleaved uints -> hi/lo bf16x8 fragments
__device__ __forceinline__ void unpack8(const unsigned* __restrict__ p,
                                        bf16x8& ah, bf16x8& al)
{
#pragma unroll
    for (int j = 0; j < 8; ++j) {
        unsigned u = p[j];
        ah[j] = (short)(u >> 16);
        al[j] = (short)(u & 0xFFFFu);
    }
}

// 3-MFMA split product accumulate
#define MFMA3(ACC, AH_, AL_, BH_, BL_)                                              \
    ACC = __builtin_amdgcn_mfma_f32_16x16x32_bf16(AH_, BH_, ACC, 0, 0, 0);          \
    ACC = __builtin_amdgcn_mfma_f32_16x16x32_bf16(AH_, BL_, ACC, 0, 0, 0);          \
    ACC = __builtin_amdgcn_mfma_f32_16x16x32_bf16(AL_, BH_, ACC, 0, 0, 0);

// ---------------------------------------------------------------------------
// Fused MLP: C = (swish(A @ B1 + b1)) @ B2 + b2[bcol0:].  Used only for the
// initial phi0 (from k_s_init's packed s).
// ---------------------------------------------------------------------------
template<int K1, int N2>
__global__ __launch_bounds__(256)
void mlp_fused(const ushort* __restrict__ AH, const ushort* __restrict__ AL,
               const ushort* __restrict__ B1h, const ushort* __restrict__ B1l,
               const float* __restrict__ b1,
               const ushort* __restrict__ B2h, const ushort* __restrict__ B2l,
               const float* __restrict__ b2, int bcol0,
               float* __restrict__ C)
{
    __shared__ float Hs[32 * LDH];
    const int tid  = threadIdx.x;
    const int lane = tid & 63;
    const int w    = tid >> 6;
    const int wm   = w & 1, wn = w >> 1;
    const int m0   = blockIdx.x * 32;
    const int l15  = lane & 15;
    const int koff = (lane >> 4) * 8;
    const int rowb = wm * 16;                   // local row base
    const int q4   = (lane >> 4) * 4;

    // ---- phase 1: H = swish(A @ B1 + b1) (N1 = 128) ----
    f32x4 acc1[4];
#pragma unroll
    for (int j = 0; j < 4; ++j) acc1[j] = (f32x4){0.f, 0.f, 0.f, 0.f};
#pragma unroll
    for (int k0 = 0; k0 < K1; k0 += 32) {
        size_t aa = (size_t)(m0 + rowb + l15) * K1 + k0 + koff;
        bf16x8 ah = *reinterpret_cast<const bf16x8*>(AH + aa);
        bf16x8 al = *reinterpret_cast<const bf16x8*>(AL + aa);
#pragma unroll
        for (int nf = 0; nf < 4; ++nf) {
            size_t ba = (size_t)(wn * 64 + nf * 16 + l15) * K1 + k0 + koff;
            bf16x8 bh = *reinterpret_cast<const bf16x8*>(B1h + ba);
            bf16x8 bl = *reinterpret_cast<const bf16x8*>(B1l + ba);
            MFMA3(acc1[nf], ah, al, bh, bl);
        }
    }
#pragma unroll
    for (int nf = 0; nf < 4; ++nf) {
        int col = wn * 64 + nf * 16 + l15;
        float bv = b1[col];
#pragma unroll
        for (int r = 0; r < 4; ++r) {
            float x = acc1[nf][r] + bv;
            x = x / (1.f + __expf(-x));         // swish
            Hs[(rowb + q4 + r) * LDH + col] = x;
        }
    }
    __syncthreads();

    // ---- phase 2: C = H @ B2 + b2 ----
    constexpr int NF2  = N2 / 32;               // frags per wave
    constexpr int WCOL = N2 / 2;
    f32x4 acc2[NF2];
#pragma unroll
    for (int j = 0; j < NF2; ++j) acc2[j] = (f32x4){0.f, 0.f, 0.f, 0.f};
#pragma unroll
    for (int k0 = 0; k0 < 128; k0 += 32) {
        const float* hp = &Hs[(rowb + l15) * LDH + k0 + koff];
        float hv[8];
#pragma unroll
        for (int j = 0; j < 8; ++j) hv[j] = hp[j];
        bf16x8 ah, al;
        splitv8(hv, ah, al);
#pragma unroll
        for (int nf = 0; nf < NF2; ++nf) {
            size_t ba = (size_t)(wn * WCOL + nf * 16 + l15) * 128 + k0 + koff;
            bf16x8 bh = *reinterpret_cast<const bf16x8*>(B2h + ba);
            bf16x8 bl = *reinterpret_cast<const bf16x8*>(B2l + ba);
            MFMA3(acc2[nf], ah, al, bh, bl);
        }
    }
#pragma unroll
    for (int nf = 0; nf < NF2; ++nf) {
        int col = wn * WCOL + nf * 16 + l15;
        float bv = b2 ? b2[bcol0 + col] : 0.f;
#pragma unroll
        for (int r = 0; r < 4; ++r) {
            int row = m0 + rowb + q4 + r;
            C[(size_t)row * N2 + col] = acc2[nf][r] + bv;
        }
    }
}

// ---------------------------------------------------------------------------
// r10 MEGA kernel: r9 structure (8-wave, vnorm + stack-MLP + u/update + dual
// MLP) + the CG-message folded into the epilogue.  k_cg_msg consumed uv that
// phase D2 holds IN REGISTERS for exactly this wave's rows/cols — the uv
// round-trip (20MB/conv), the 20000-block launch, and its 200MB/conv L2
// weight re-read are all removed.  conv0's s_add term is phase C's ns (still
// in registers).  S_acc is accumulated across convs (cnt is conv-invariant;
// single divide at the end differs by ~1ulp from per-conv divides).
// ---------------------------------------------------------------------------
template<int HAS_MSG, int SADD>
__global__ __launch_bounds__(512, 4)
void k_update_mega(unsigned* __restrict__ vP,
                   const ushort* __restrict__ catH, const ushort* __restrict__ catL,
                   const ushort* __restrict__ BVh, const ushort* __restrict__ BVl,
                   const ushort* __restrict__ W1h, const ushort* __restrict__ W1l,
                   const float*  __restrict__ b1,
                   const ushort* __restrict__ W2h, const ushort* __restrict__ W2l,
                   const float*  __restrict__ b2,
                   const ushort* __restrict__ BUh, const ushort* __restrict__ BUl,
                   float* __restrict__ s,
                   const ushort* __restrict__ M1h, const ushort* __restrict__ M1l,
                   const float*  __restrict__ m1b,
                   const ushort* __restrict__ M2h, const ushort* __restrict__ M2l,
                   const float*  __restrict__ m2b,
                   const ushort* __restrict__ C1h, const ushort* __restrict__ C1l,
                   const float*  __restrict__ c1b,
                   const ushort* __restrict__ C2h, const ushort* __restrict__ C2l,
                   const float*  __restrict__ c2b,      // full 384; cols 128.. used
                   float* __restrict__ phi,
                   const float* __restrict__ cdW, const float* __restrict__ cdb,
                   const int*   __restrict__ mapping,
                   const float* __restrict__ env_a, const float* __restrict__ rbf_a,
                   float* __restrict__ S_acc)
{
    // region0 Hs/Hm (16640B) | region1 nH,nL -> sHs,sLs (2*32*136*2 = 17408B)
    // | region2 Hc (16640B)  = 50688B
    __shared__ __align__(16) char smem[16640 + 17408 + 16640];
    float*  Hs  = (float*)smem;                          // region0 (also Hm)
    ushort* nH  = (ushort*)(smem + 16640);               // region1
    ushort* nL  = (ushort*)(smem + 16640 + 32 * SPAD * 2);
    ushort* sHs = nH;                                    // region1 reuse (post-B1)
    ushort* sLs = nL;
    float*  Hc  = (float*)(smem + 16640 + 17408);        // region2

    const int tid  = threadIdx.x;
    const int lane = tid & 63;
    const int w    = tid >> 6;                  // 0..7
    const int wm   = w & 1, wn = w >> 1;        // wn 0..3 (32-col quarter)
    const int m0   = blockIdx.x * 32;
    const int l15  = lane & 15;
    const int koff = (lane >> 4) * 8;
    const int rowb = wm * 16;
    const int q4   = (lane >> 4) * 4;

    // ---- phase A: dual GEMM (vv = v@V, uv = v@U) with a single A pass ----
    f32x4 accV[3][2], accU[3][2];
#pragma unroll
    for (int d = 0; d < 3; ++d)
#pragma unroll
        for (int j = 0; j < 2; ++j) {
            accV[d][j] = (f32x4){0.f, 0.f, 0.f, 0.f};
            accU[d][j] = (f32x4){0.f, 0.f, 0.f, 0.f};
        }
#pragma unroll
    for (int k0 = 0; k0 < 128; k0 += 32) {
        bf16x8 ah[3], al[3];
#pragma unroll
        for (int d = 0; d < 3; ++d) {
            size_t aa = (size_t)d * PLANE + (size_t)(m0 + rowb + l15) * 128 + k0 + koff;
            unsigned u[8];
#pragma unroll
            for (int j = 0; j < 8; ++j) u[j] = vP[aa + j];
            unpack8(u, ah[d], al[d]);
        }
#pragma unroll
        for (int nf = 0; nf < 2; ++nf) {
            size_t ba = (size_t)(wn * 32 + nf * 16 + l15) * 128 + k0 + koff;
            bf16x8 bvh = *reinterpret_cast<const bf16x8*>(BVh + ba);
            bf16x8 bvl = *reinterpret_cast<const bf16x8*>(BVl + ba);
            bf16x8 buh = *reinterpret_cast<const bf16x8*>(BUh + ba);
            bf16x8 bul = *reinterpret_cast<const bf16x8*>(BUl + ba);
#pragma unroll
            for (int d = 0; d < 3; ++d) {
                MFMA3(accV[d][nf], ah[d], al[d], bvh, bvl);
            }
#pragma unroll
            for (int d = 0; d < 3; ++d) {
                MFMA3(accU[d][nf], ah[d], al[d], buh, bul);
            }
        }
    }
    // norm -> LDS
#pragma unroll
    for (int nf = 0; nf < 2; ++nf) {
        int col = wn * 32 + nf * 16 + l15;
#pragma unroll
        for (int r = 0; r < 4; ++r) {
            int lrow = rowb + q4 + r;
            float x = accV[0][nf][r], y = accV[1][nf][r], z = accV[2][nf][r];
            float nrm = sqrtf(x * x + y * y + z * z + 3e-15f);
            ushort h, l;
            split2(nrm, h, l);
            nH[lrow * SPAD + col] = h;
            nL[lrow * SPAD + col] = l;
        }
    }
    __syncthreads();

    // ---- phase B1: H = swish([Ccat_s | norm] @ W1 + b1), K1 = 256 ----
    f32x4 acc1[2];
#pragma unroll
    for (int j = 0; j < 2; ++j) acc1[j] = (f32x4){0.f, 0.f, 0.f, 0.f};
#pragma unroll
    for (int k0 = 0; k0 < 256; k0 += 32) {
        bf16x8 ah, al;
        if (k0 < 128) {
            size_t aa = (size_t)(m0 + rowb + l15) * 128 + k0 + koff;
            ah = *reinterpret_cast<const bf16x8*>(catH + aa);
            al = *reinterpret_cast<const bf16x8*>(catL + aa);
        } else {
            int la = (rowb + l15) * SPAD + (k0 - 128) + koff;
            ah = *reinterpret_cast<const bf16x8*>(nH + la);
            al = *reinterpret_cast<const bf16x8*>(nL + la);
        }
#pragma unroll
        for (int nf = 0; nf < 2; ++nf) {
            size_t ba = (size_t)(wn * 32 + nf * 16 + l15) * 256 + k0 + koff;
            bf16x8 bh = *reinterpret_cast<const bf16x8*>(W1h + ba);
            bf16x8 bl = *reinterpret_cast<const bf16x8*>(W1l + ba);
            MFMA3(acc1[nf], ah, al, bh, bl);
        }
    }
#pragma unroll
    for (int nf = 0; nf < 2; ++nf) {
        int col = wn * 32 + nf * 16 + l15;
        float bv = b1[col];
#pragma unroll
        for (int r = 0; r < 4; ++r) {
            float x = acc1[nf][r] + bv;
            x = x / (1.f + __expf(-x));         // swish
            Hs[(rowb + q4 + r) * LDH + col] = x;
        }
    }
    __syncthreads();   // nH/nL reads done block-wide; region1 reusable below

    // ---- phase B2: stack fragments IN REGISTERS, wave-aligned to phase C ----
    // group g: 0=avv, 1=asv, 2=ass; col = g*128 + wn*32 + j*16 + l15
    f32x4 acc2[6];
#pragma unroll
    for (int j = 0; j < 6; ++j) acc2[j] = (f32x4){0.f, 0.f, 0.f, 0.f};
#pragma unroll
    for (int k0 = 0; k0 < 128; k0 += 32) {
        const float* hp = &Hs[(rowb + l15) * LDH + k0 + koff];
        float hv[8];
#pragma unroll
        for (int j = 0; j < 8; ++j) hv[j] = hp[j];
        bf16x8 ah, al;
        splitv8(hv, ah, al);
#pragma unroll
        for (int g = 0; g < 3; ++g) {
#pragma unroll
            for (int j = 0; j < 2; ++j) {
                size_t ba = (size_t)(g * 128 + wn * 32 + j * 16 + l15) * 128 + k0 + koff;
                bf16x8 bh = *reinterpret_cast<const bf16x8*>(W2h + ba);
                bf16x8 bl = *reinterpret_cast<const bf16x8*>(W2l + ba);
                MFMA3(acc2[g * 2 + j], ah, al, bh, bl);
            }
        }
    }

    // ---- phase C: update rule; new packed s -> LDS; ns kept for SADD ----
    float nsav[2][4];
#pragma unroll
    for (int nf = 0; nf < 2; ++nf) {
        int col = wn * 32 + nf * 16 + l15;
        float bavv = b2[col];
        float basv = b2[128 + col];
        float bass = b2[256 + col];
#pragma unroll
        for (int r = 0; r < 4; ++r) {
            int lrow = rowb + q4 + r;
            int row  = m0 + lrow;
            size_t idx = (size_t)row * FEAT + col;
            float avv = acc2[nf][r]     + bavv;
            float asv = acc2[2 + nf][r] + basv;
            float ass = acc2[4 + nf][r] + bass;
            float u0 = accU[0][nf][r], u1 = accU[1][nf][r], u2 = accU[2][nf][r];
            float w0 = accV[0][nf][r], w1 = accV[1][nf][r], w2 = accV[2][nf][r];
            float dot = u0 * w0 + u1 * w1 + u2 * w2;
            float n0 = reconP(vP[idx])                      + u0 * avv;
            float n1 = reconP(vP[PLANE + idx])              + u1 * avv;
            float n2 = reconP(vP[2 * (size_t)PLANE + idx])  + u2 * avv;
            vP[idx] = packP(n0);
            vP[PLANE + idx] = packP(n1);
            vP[2 * (size_t)PLANE + idx] = packP(n2);
            float ns = s[idx] + dot * asv + ass;
            s[idx] = ns;
            nsav[nf][r] = ns;
            ushort h, l;
            split2(ns, h, l);
            sHs[lrow * SPAD + col] = h;
            sLs[lrow * SPAD + col] = l;
        }
    }
    __syncthreads();

    // ---- phase D1: hidden layers of msg (next conv) and cg MLPs from LDS s ----
    f32x4 am[2], ac[2];
#pragma unroll
    for (int j = 0; j < 2; ++j) {
        am[j] = (f32x4){0.f, 0.f, 0.f, 0.f};
        ac[j] = (f32x4){0.f, 0.f, 0.f, 0.f};
    }
#pragma unroll
    for (int k0 = 0; k0 < 128; k0 += 32) {
        int la = (rowb + l15) * SPAD + k0 + koff;
        bf16x8 ah = *reinterpret_cast<const bf16x8*>(sHs + la);
        bf16x8 al = *reinterpret_cast<const bf16x8*>(sLs + la);
#pragma unroll
        for (int nf = 0; nf < 2; ++nf) {
            size_t ba = (size_t)(wn * 32 + nf * 16 + l15) * 128 + k0 + koff;
            if (HAS_MSG) {
                bf16x8 bh = *reinterpret_cast<const bf16x8*>(M1h + ba);
                bf16x8 bl = *reinterpret_cast<const bf16x8*>(M1l + ba);
                MFMA3(am[nf], ah, al, bh, bl);
            }
            bf16x8 ch = *reinterpret_cast<const bf16x8*>(C1h + ba);
            bf16x8 cl = *reinterpret_cast<const bf16x8*>(C1l + ba);
            MFMA3(ac[nf], ah, al, ch, cl);
        }
    }
#pragma unroll
    for (int nf = 0; nf < 2; ++nf) {
        int col = wn * 32 + nf * 16 + l15;
        float bvc = c1b[col];
        float bvm = HAS_MSG ? m1b[col] : 0.f;
#pragma unroll
        for (int r = 0; r < 4; ++r) {
            int lr = rowb + q4 + r;
            if (HAS_MSG) {
                float x = am[nf][r] + bvm;
                Hs[lr * LDH + col] = x / (1.f + __expf(-x));   // Hm (region0)
            }
            float y = ac[nf][r] + bvc;
            Hc[lr * LDH + col] = y / (1.f + __expf(-y));
        }
    }
    __syncthreads();

    // ---- phase D2: phi (384, msg; 96 cols/wave) and uv (128, cg; in regs) ----
    f32x4 a2m[6], a2c[2];
    if (HAS_MSG) {
#pragma unroll
        for (int j = 0; j < 6; ++j) a2m[j] = (f32x4){0.f, 0.f, 0.f, 0.f};
    }
#pragma unroll
    for (int j = 0; j < 2; ++j)  a2c[j] = (f32x4){0.f, 0.f, 0.f, 0.f};
#pragma unroll
    for (int k0 = 0; k0 < 128; k0 += 32) {
        const float* hpc = &Hc[(rowb + l15) * LDH + k0 + koff];
        float hvc[8];
#pragma unroll
        for (int j = 0; j < 8; ++j) hvc[j] = hpc[j];
        bf16x8 ahc, alc;
        splitv8(hvc, ahc, alc);
#pragma unroll
        for (int nf = 0; nf < 2; ++nf) {
            size_t ba = (size_t)(wn * 32 + nf * 16 + l15) * 128 + k0 + koff;
            bf16x8 bh = *reinterpret_cast<const bf16x8*>(C2h + ba);
            bf16x8 bl = *reinterpret_cast<const bf16x8*>(C2l + ba);
            MFMA3(a2c[nf], ahc, alc, bh, bl);
        }
        if (HAS_MSG) {
            const float* hpm = &Hs[(rowb + l15) * LDH + k0 + koff];
            float hvm[8];
#pragma unroll
            for (int j = 0; j < 8; ++j) hvm[j] = hpm[j];
            bf16x8 ahm, alm;
            splitv8(hvm, ahm, alm);
#pragma unroll
            for (int nf = 0; nf < 6; ++nf) {
                size_t ba = (size_t)(wn * 96 + nf * 16 + l15) * 128 + k0 + koff;
                bf16x8 bh = *reinterpret_cast<const bf16x8*>(M2h + ba);
                bf16x8 bl = *reinterpret_cast<const bf16x8*>(M2l + ba);
                MFMA3(a2m[nf], ahm, alm, bh, bl);
            }
        }
    }
    if (HAS_MSG) {
#pragma unroll
        for (int nf = 0; nf < 6; ++nf) {
            int col = wn * 96 + nf * 16 + l15;
            float bv = m2b[col];
#pragma unroll
            for (int r = 0; r < 4; ++r) {
                int row = m0 + rowb + q4 + r;
                phi[(size_t)row * 384 + col] = a2m[nf][r] + bv;
            }
        }
    }

    // ---- epilogue: CG message accumulate (replaces k_cg_msg) ----
    // per-lane cg_dist weights for this lane's 2 columns (mid-128 band)
    float wc0[21], wc1[21];
    {
        int c0 = wn * 32 + l15;
        int c1 = wn * 32 + 16 + l15;
#pragma unroll
        for (int k = 0; k < NRBF; ++k) {
            wc0[k] = cdW[k * 384 + 128 + c0];
            wc1[k] = cdW[k * 384 + 128 + c1];
        }
        wc0[20] = cdb[128 + c0];
        wc1[20] = cdb[128 + c1];
    }
#pragma unroll
    for (int r = 0; r < 4; ++r) {
        int lrow = rowb + q4 + r;
        int n    = m0 + lrow;
        float env = env_a[n];
        int   m   = mapping[n];
        float rb[NRBF];
#pragma unroll
        for (int k = 0; k < NRBF; ++k) rb[k] = rbf_a[(size_t)n * NRBF + k];
#pragma unroll
        for (int nf = 0; nf < 2; ++nf) {
            int col = wn * 32 + nf * 16 + l15;
            const float* wc = nf ? wc1 : wc0;
            float val = SADD ? nsav[nf][r] : 0.f;
            if (env != 0.f) {
                float w1s = 0.f;
#pragma unroll
                for (int k = 0; k < NRBF; ++k) w1s += rb[k] * wc[k];
                w1s += wc[20] * env;
                float uvv = a2c[nf][r] + c2b[128 + col];
                val += uvv * w1s;
            }
            if (SADD || env != 0.f)
                atomicAdd(&S_acc[(size_t)m * FEAT + col], val);
        }
    }
}

// ---------------------------------------------------------------------------
// Weight pre-pack: fp32 W[k][col0+n] -> bf16 hi/lo at [n][k] (k-contiguous).
// ---------------------------------------------------------------------------
__global__ void k_pack_all(const float* __restrict__ msg_W1, const float* __restrict__ msg_W2,
                           const float* __restrict__ upd_V,  const float* __restrict__ upd_W1,
                           const float* __restrict__ upd_W2, const float* __restrict__ upd_U,
                           const float* __restrict__ cg_W1,  const float* __restrict__ cg_W2,
                           ushort* __restrict__ Bh, ushort* __restrict__ Bl)
{
    const int wid = blockIdx.y, conv = blockIdx.z;
    const float* W; int K, N, ldw, col0; size_t off;
    switch (wid) {
        case 0: W = msg_W1 + (size_t)conv * 16384; K = 128; N = 128; ldw = 128; col0 = 0;   off = 0;      break;
        case 1: W = msg_W2 + (size_t)conv * 49152; K = 128; N = 384; ldw = 384; col0 = 0;   off = 16384;  break;
        case 2: W = upd_V  + (size_t)conv * 16384; K = 128; N = 128; ldw = 128; col0 = 0;   off = 65536;  break;
        case 3: W = upd_W1 + (size_t)conv * 32768; K = 256; N = 128; ldw = 128; col0 = 0;   off = 81920;  break;
        case 4: W = upd_W2 + (size_t)conv * 49152; K = 128; N = 384; ldw = 384; col0 = 0;   off = 114688; break;
        case 5: W = upd_U  + (size_t)conv * 16384; K = 128; N = 128; ldw = 128; col0 = 0;   off = 163840; break;
        case 6: W = cg_W1  + (size_t)conv * 16384; K = 128; N = 128; ldw = 128; col0 = 0;   off = 180224; break;
        default:W = cg_W2  + (size_t)conv * 49152; K = 128; N = 128; ldw = 384; col0 = 128; off = 196608; break;
    }
    off += (size_t)conv * PACK_PER_CONV;
    int idx = blockIdx.x * 256 + threadIdx.x;
    if (idx >= K * N) return;
    int k = idx & (K - 1);
    int n = idx >> ((K == 256) ? 8 : 7);
    ushort h, l;
    split2(W[(size_t)k * ldw + col0 + n], h, l);
    Bh[off + (size_t)n * K + k] = h;
    Bl[off + (size_t)n * K + k] = l;
}

// ---------------------------------------------------------------------------
// Setup kernels
// ---------------------------------------------------------------------------
__global__ void k_s_init(const int* __restrict__ z, const float* __restrict__ embed,
                         float* __restrict__ s, ushort* __restrict__ sH, ushort* __restrict__ sL)
{
    int idx = blockIdx.x * blockDim.x + threadIdx.x;
    if (idx >= PLANE) return;
    int n = idx >> 7, g = idx & 127;
    float e = embed[z[n] * FEAT + g];
    s[idx] = e;
    ushort h, l;
    split2(e, h, l);
    sH[idx] = h; sL[idx] = l;
}

__global__ void k_atom_geo(const int* __restrict__ mapping,
                           const float* __restrict__ xyz, const float* __restrict__ cg_xyz,
                           float* __restrict__ rbf_a, float* __restrict__ env_a,
                           float* __restrict__ cnt)
{
    int n = blockIdx.x * blockDim.x + threadIdx.x;
    if (n >= N_ATOMS) return;
    int m = mapping[n];
    float dx = xyz[n * 3 + 0] - cg_xyz[m * 3 + 0];
    float dy = xyz[n * 3 + 1] - cg_xyz[m * 3 + 1];
    float dz = xyz[n * 3 + 2] - cg_xyz[m * 3 + 2];
    float d = sqrtf(dx * dx + dy * dy + dz * dz + 3e-15f);
    float env = (d < CUTOFF) ? 0.5f * (cosf(PI_F * d / CUTOFF) + 1.f) : 0.f;
    env_a[n] = env;
    float s = env / d;
#pragma unroll
    for (int k = 0; k < NRBF; ++k)
        rbf_a[n * NRBF + k] = sinf((k + 1) * PI_F * d / CUTOFF) * s;
    atomicAdd(&cnt[m], 1.f);
}

// ---------------------------------------------------------------------------
// CSR build
// ---------------------------------------------------------------------------
__global__ void k_deg(const int* __restrict__ nbr, int* __restrict__ deg)
{
    int e = blockIdx.x * blockDim.x + threadIdx.x;
    if (e < N_EDGES) atomicAdd(&deg[nbr[2 * e]], 1);
}

__global__ __launch_bounds__(1024)
void k_scan(const int* __restrict__ deg, int* __restrict__ rowptr)
{
    __shared__ int sh[1024];
    const int chunk = (N_ATOMS + 1023) / 1024;
    int t = threadIdx.x;
    int base = t * chunk;
    int sum = 0;
    for (int i = 0; i < chunk; ++i) {
        int idx = base + i;
        if (idx < N_ATOMS) sum += deg[idx];
    }
    sh[t] = sum;
    __syncthreads();
    for (int off = 1; off < 1024; off <<= 1) {
        int val = (t >= off) ? sh[t - off] : 0;
        __syncthreads();
        sh[t] += val;
        __syncthreads();
    }
    int run = (t == 0) ? 0 : sh[t - 1];
    for (int i = 0; i < chunk; ++i) {
        int idx = base + i;
        if (idx < N_ATOMS) { rowptr[idx] = run; run += deg[idx]; }
    }
}

__global__ void k_fill(const int* __restrict__ nbr, const float* __restrict__ xyz,
                       const int* __restrict__ rowptr, int* __restrict__ cursor,
                       int* __restrict__ rec_dst, float4* __restrict__ rec_u4,
                       float* __restrict__ rec_rbf)
{
    int e = blockIdx.x * blockDim.x + threadIdx.x;
    if (e >= N_EDGES) return;
    int src = nbr[2 * e], dst = nbr[2 * e + 1];
    int pos = atomicAdd(&cursor[src], 1);
    int q = rowptr[src] + pos;
    float dx = xyz[dst * 3 + 0] - xyz[src * 3 + 0];
    float dy = xyz[dst * 3 + 1] - xyz[src * 3 + 1];
    float dz = xyz[dst * 3 + 2] - xyz[src * 3 + 2];
    float d = sqrtf(dx * dx + dy * dy + dz * dz + 3e-15f);
    float env = (d < CUTOFF) ? 0.5f * (cosf(PI_F * d / CUTOFF) + 1.f) : 0.f;
    rec_dst[q] = dst;
    rec_u4[q] = make_float4(dx / d, dy / d, dz / d, env);
    float sc = env / d;
#pragma unroll
    for (int k = 0; k < NRBF; ++k)
        rec_rbf[(size_t)q * NRBF + k] = sinf((k + 1) * PI_F * d / CUTOFF) * sc;
}

// ---------------------------------------------------------------------------
// Edge segment-sum (r2 slot-per-atom, r4 2-edge ILP, r6 interleaved packed v).
// At its memory-path floor (~313 MB L2-miss stream, invariant r0-r9).
// ---------------------------------------------------------------------------
#define EDGE_BLOCKS 2500
__global__ __launch_bounds__(512, 2)
void k_edge_seg(const int* __restrict__ rowptr, const int* __restrict__ deg,
                const int* __restrict__ rec_dst, const float4* __restrict__ rec_u4,
                const float* __restrict__ rec_rbf,
                const float* __restrict__ phi,
                const unsigned* __restrict__ vPi, unsigned* __restrict__ vPo,
                float* __restrict__ s,
                ushort* __restrict__ catH, ushort* __restrict__ catL,
                const float* __restrict__ distW, const float* __restrict__ distb)
{
    const int tid    = threadIdx.x;
    const int slot   = tid >> 7;                // 0..3 within block
    const int f      = tid & 127;
    const int slot_g = blockIdx.x * 4 + slot;   // global slot id
    const int nslots = EDGE_BLOCKS * 4;         // 10000 slots, 2 atoms each

    // per-lane weight registers: k=20 is the bias row
    float wx[21], wy[21], wz[21];
#pragma unroll
    for (int k = 0; k < NRBF; ++k) {
        wx[k] = distW[k * 384 + f];
        wy[k] = distW[k * 384 + 128 + f];
        wz[k] = distW[k * 384 + 256 + f];
    }
    wx[20] = distb[f];
    wy[20] = distb[128 + f];
    wz[20] = distb[256 + f];
#pragma unroll
    for (int k = 0; k < 21; ++k) {
        asm volatile("" : "+v"(wx[k]), "+v"(wy[k]), "+v"(wz[k]));
    }

    for (int a = slot_g; a < N_ATOMS; a += nslots) {
        const int beg = rowptr[a];
        const int end = beg + deg[a];
        float s_acc = 0.f, vx = 0.f, vy = 0.f, vz = 0.f;

        for (int p = beg; p < end; p += 2) {
            const int  has2 = (p + 1 < end);
            const int  p1   = has2 ? p + 1 : p;
            const float m1  = has2 ? 1.f : 0.f;

            // headers (slot-uniform)
            float4 u40 = rec_u4[p];
            float4 u41 = rec_u4[p1];
            int dst0 = rec_dst[p];
            int dst1 = rec_dst[p1];

            // gathers for BOTH edges issued back-to-back (independent chains)
            const float* ph0 = phi + (size_t)dst0 * 384 + f;
            const float* ph1 = phi + (size_t)dst1 * 384 + f;
            float p00 = ph0[0], p01 = ph0[128], p02 = ph0[256];
            float p10 = ph1[0], p11 = ph1[128], p12 = ph1[256];
            size_t di0 = (size_t)dst0 * FEAT + f;
            size_t di1 = (size_t)dst1 * FEAT + f;
            float v0x = reconP(vPi[di0]);
            float v0y = reconP(vPi[PLANE + di0]);
            float v0z = reconP(vPi[2 * (size_t)PLANE + di0]);
            float v1x = reconP(vPi[di1]);
            float v1y = reconP(vPi[PLANE + di1]);
            float v1z = reconP(vPi[2 * (size_t)PLANE + di1]);
            const float4* rb0 = reinterpret_cast<const float4*>(rec_rbf + (size_t)p  * NRBF);
            const float4* rb1 = reinterpret_cast<const float4*>(rec_rbf + (size_t)p1 * NRBF);
            float4 a0 = rb0[0], a1 = rb0[1], a2 = rb0[2], a3 = rb0[3], a4 = rb0[4];
            float4 b0 = rb1[0], b1 = rb1[1], b2 = rb1[2], b3 = rb1[3], b4 = rb1[4];

            const float rr0[21] = {a0.x, a0.y, a0.z, a0.w, a1.x, a1.y, a1.z, a1.w,
                                   a2.x, a2.y, a2.z, a2.w, a3.x, a3.y, a3.z, a3.w,
                                   a4.x, a4.y, a4.z, a4.w, u40.w};
            const float rr1[21] = {b0.x, b0.y, b0.z, b0.w, b1.x, b1.y, b1.z, b1.w,
                                   b2.x, b2.y, b2.z, b2.w, b3.x, b3.y, b3.z, b3.w,
                                   b4.x, b4.y, b4.z, b4.w, u41.w};
            float w00 = 0.f, w01 = 0.f, w02 = 0.f;
            float w10 = 0.f, w11 = 0.f, w12 = 0.f;
#pragma unroll
            for (int k = 0; k < 21; ++k) {
                w00 += rr0[k] * wx[k];
                w01 += rr0[k] * wy[k];
                w02 += rr0[k] * wz[k];
                w10 += rr1[k] * wx[k];
                w11 += rr1[k] * wy[k];
                w12 += rr1[k] * wz[k];
            }
            float i00 = p00 * w00, i01 = p01 * w01, i02 = p02 * w02;
            float i10 = (p10 * w10) * m1, i11 = (p11 * w11) * m1, i12 = (p12 * w12) * m1;
            // sequential accumulation: e0 then e1 (order-preserving)
            vx += i02 * u40.x + i00 * v0x;
            vy += i02 * u40.y + i00 * v0y;
            vz += i02 * u40.z + i00 * v0z;
            s_acc += i01;
            vx += i12 * u41.x + i10 * v1x;
            vy += i12 * u41.y + i10 * v1y;
            vz += i12 * u41.z + i10 * v1z;
            s_acc += i11;
        }

        // epilogue: this slot's 128 lanes write atom a's outputs
        size_t si = (size_t)a * FEAT + f;
        float ns = s[si] + s_acc;
        s[si] = ns;
        float nx = reconP(vPi[si])                     + vx;
        float ny = reconP(vPi[PLANE + si])             + vy;
        float nz = reconP(vPi[2 * (size_t)PLANE + si]) + vz;
        vPo[si] = packP(nx);
        vPo[PLANE + si] = packP(ny);
        vPo[2 * (size_t)PLANE + si] = packP(nz);
        ushort h, l;
        split2(ns, h, l);
        catH[(size_t)a * 128 + f] = h;
        catL[(size_t)a * 128 + f] = l;
    }
}

__global__ void k_finalize(const float* __restrict__ S_acc, const float* __restrict__ cnt,
                           float* __restrict__ out)
{
    int idx = blockIdx.x * blockDim.x + threadIdx.x;
    if (idx >= N_CG * FEAT) return;
    out[idx] = S_acc[idx] / fmaxf(cnt[idx >> 7], 1.f);
}

// ---------------------------------------------------------------------------
extern "C" void kernel_launch(void* const* d_in, const int* in_sizes, int n_in,
                              void* d_out, int out_size, void* d_ws, size_t ws_size,
                              hipStream_t stream)
{
    const int*   z        = (const int*)d_in[0];
    const float* xyz      = (const float*)d_in[1];
    const float* cg_xyz   = (const float*)d_in[2];
    const int*   mapping  = (const int*)d_in[3];
    const int*   nbr      = (const int*)d_in[4];
    const float* embed    = (const float*)d_in[5];
    const float* msg_W1   = (const float*)d_in[6];
    const float* msg_b1   = (const float*)d_in[7];
    const float* msg_W2   = (const float*)d_in[8];
    const float* msg_b2   = (const float*)d_in[9];
    const float* msg_dW   = (const float*)d_in[10];
    const float* msg_db   = (const float*)d_in[11];
    const float* upd_U    = (const float*)d_in[12];
    const float* upd_V    = (const float*)d_in[13];
    const float* upd_W1   = (const float*)d_in[14];
    const float* upd_b1   = (const float*)d_in[15];
    const float* upd_W2   = (const float*)d_in[16];
    const float* upd_b2   = (const float*)d_in[17];
    const float* cg_W1    = (const float*)d_in[18];
    const float* cg_b1    = (const float*)d_in[19];
    const float* cg_W2    = (const float*)d_in[20];
    const float* cg_b2    = (const float*)d_in[21];
    const float* cg_dW    = (const float*)d_in[22];
    const float* cg_db    = (const float*)d_in[23];
    float* out = (float*)d_out;

    float* ws = (float*)d_ws;
    size_t o = 0;
    float* s      = ws + o; o += PLANE;
    float* phi    = ws + o; o += (size_t)N_ATOMS * 384; // phi
    float* catpk  = ws + o; o += PLANE;                 // Ccat s-half hi+lo
    float* spk    = ws + o; o += PLANE;                 // packed s (initial only)
    unsigned* vPA = (unsigned*)(ws + o); o += 3 * PLANE; // packed v buffer A
    unsigned* vPB = (unsigned*)(ws + o); o += 3 * PLANE; // packed v buffer B
    float4* rec_u4 = (float4*)(ws + o); o += (size_t)N_EDGES * 4;
    float* rec_rbf = ws + o; o += (size_t)N_EDGES * NRBF;
    int*   rec_dst = (int*)(ws + o); o += N_EDGES;
    float* rbf_a  = ws + o; o += (size_t)N_ATOMS * NRBF;
    float* env_a  = ws + o; o += N_ATOMS;
    float* cnt    = ws + o; o += N_CG;
    float* S_acc  = ws + o; o += N_CG * FEAT;           // accumulated across convs
    int*   deg    = (int*)(ws + o); o += N_ATOMS;
    int*   rowptr = (int*)(ws + o); o += N_ATOMS;
    int*   cursor = (int*)(ws + o); o += N_ATOMS;
    ushort* packH = (ushort*)(ws + o); o += (size_t)NCONV * PACK_PER_CONV / 2;
    ushort* packL = (ushort*)(ws + o); o += (size_t)NCONV * PACK_PER_CONV / 2;

    ushort* catH = (ushort*)catpk; ushort* catL = catH + (size_t)N_ATOMS * 128;
    ushort* sH = (ushort*)spk;  ushort* sL = sH + PLANE;

    // ---- setup ----
    hipMemsetAsync(vPA, 0, sizeof(unsigned) * 3 * PLANE, stream);  // v = 0
    hipMemsetAsync(cnt, 0, sizeof(float) * N_CG, stream);
    hipMemsetAsync(deg, 0, sizeof(int) * N_ATOMS, stream);
    hipMemsetAsync(cursor, 0, sizeof(int) * N_ATOMS, stream);
    hipMemsetAsync(S_acc, 0, sizeof(float) * N_CG * FEAT, stream);
    k_pack_all<<<dim3(192, 8, 3), 256, 0, stream>>>(msg_W1, msg_W2, upd_V, upd_W1,
                                                    upd_W2, upd_U, cg_W1, cg_W2,
                                                    packH, packL);
    k_s_init<<<(PLANE + 255) / 256, 256, 0, stream>>>(z, embed, s, sH, sL);
    k_atom_geo<<<(N_ATOMS + 255) / 256, 256, 0, stream>>>(mapping, xyz, cg_xyz,
                                                          rbf_a, env_a, cnt);
    k_deg<<<(N_EDGES + 255) / 256, 256, 0, stream>>>(nbr, deg);
    k_scan<<<1, 1024, 0, stream>>>(deg, rowptr);
    k_fill<<<(N_EDGES + 255) / 256, 256, 0, stream>>>(nbr, xyz, rowptr, cursor,
                                                      rec_dst, rec_u4, rec_rbf);

    unsigned* vPc = vPA;    // current (gather source)
    unsigned* vPn = vPB;    // next (write target)

    // phi0 = msg MLP on the initial s
    mlp_fused<128, 384><<<625, 256, 0, stream>>>(
        sH, sL, packH + 0, packL + 0, msg_b1,
        packH + 16384, packL + 16384, msg_b2, 0, phi);

    for (int i = 0; i < NCONV; ++i) {
        const float* ub1 = upd_b1 + (size_t)i * FEAT;
        const float* ub2 = upd_b2 + (size_t)i * 384;
        const float* mdW = msg_dW + (size_t)i * NRBF * 384;
        const float* mdb = msg_db + (size_t)i * 384;
        const float* cb1 = cg_b1  + (size_t)i * FEAT;
        const float* cb2 = cg_b2  + (size_t)i * 384;
        const float* cdW = cg_dW  + (size_t)i * NRBF * 384;
        const float* cdb = cg_db  + (size_t)i * 384;
        const size_t pb  = (size_t)i * PACK_PER_CONV;

        k_edge_seg<<<EDGE_BLOCKS, 512, 0, stream>>>(rowptr, deg, rec_dst, rec_u4,
                                                    rec_rbf, phi, vPc, vPn, s,
                                                    catH, catL, mdW, mdb);

        // fused update block + dual MLP + in-kernel CG message accumulate
        const size_t pn = (size_t)((i + 1 < NCONV) ? (i + 1) : i) * PACK_PER_CONV;
        if (i == 0) {
            k_update_mega<1, 1><<<625, 512, 0, stream>>>(
                vPn, catH, catL,
                packH + pb + 65536,  packL + pb + 65536,
                packH + pb + 81920,  packL + pb + 81920, ub1,
                packH + pb + 114688, packL + pb + 114688, ub2,
                packH + pb + 163840, packL + pb + 163840,
                s,
                packH + pn + 0,      packL + pn + 0,      msg_b1 + (size_t)(i + 1) * FEAT,
                packH + pn + 16384,  packL + pn + 16384,  msg_b2 + (size_t)(i + 1) * 384,
                packH + pb + 180224, packL + pb + 180224, cb1,
                packH + pb + 196608, packL + pb + 196608, cb2,
                phi, cdW, cdb, mapping, env_a, rbf_a, S_acc);
        } else if (i < NCONV - 1) {
            k_update_mega<1, 0><<<625, 512, 0, stream>>>(
                vPn, catH, catL,
                packH + pb + 65536,  packL + pb + 65536,
                packH + pb + 81920,  packL + pb + 81920, ub1,
                packH + pb + 114688, packL + pb + 114688, ub2,
                packH + pb + 163840, packL + pb + 163840,
                s,
                packH + pn + 0,      packL + pn + 0,      msg_b1 + (size_t)(i + 1) * FEAT,
                packH + pn + 16384,  packL + pn + 16384,  msg_b2 + (size_t)(i + 1) * 384,
                packH + pb + 180224, packL + pb + 180224, cb1,
                packH + pb + 196608, packL + pb + 196608, cb2,
                phi, cdW, cdb, mapping, env_a, rbf_a, S_acc);
        } else {
            k_update_mega<0, 0><<<625, 512, 0, stream>>>(
                vPn, catH, catL,
                packH + pb + 65536,  packL + pb + 65536,
                packH + pb + 81920,  packL + pb + 81920, ub1,
                packH + pb + 114688, packL + pb + 114688, ub2,
                packH + pb + 163840, packL + pb + 163840,
                s,
                nullptr, nullptr, nullptr, nullptr, nullptr, nullptr,
                packH + pb + 180224, packL + pb + 180224, cb1,
                packH + pb + 196608, packL + pb + 196608, cb2,
                phi, cdW, cdb, mapping, env_a, rbf_a, S_acc);
        }

        // swap packed v buffers
        unsigned* t = vPn; vPn = vPc; vPc = t;
    }

    // single finalize: out = S_acc / cnt  (cnt is conv-invariant)
    k_finalize<<<(N_CG * FEAT + 255) / 256, 256, 0, stream>>>(S_acc, cnt, out);
}